// Round 1
// baseline (2038.403 us; speedup 1.0000x reference)
//
#include <hip/hip_runtime.h>

#define N0 200000
#define N1 50000
#define N2 10000
#define E1 1000000
#define E2 250000
#define CIN 128
#define HD  256

// ---------------------------------------------------------------------------
// Edge scatter, C=128: one wave per edge. Lane i handles float2 at col 2*i.
// Coalesced 512B row gather from x; HW f32 atomics into agg.
// ---------------------------------------------------------------------------
__global__ __launch_bounds__(256) void scatter_k128(
    const float* __restrict__ x, const int* __restrict__ src,
    const int* __restrict__ dst, float* __restrict__ agg,
    float* __restrict__ cnt)
{
    const int e    = blockIdx.x * 4 + (threadIdx.x >> 6);
    const int lane = threadIdx.x & 63;
    const int s = src[e];
    const int d = dst[e];
    const float2 v = *(const float2*)(x + (size_t)s * CIN + lane * 2);
    float* a = agg + (size_t)d * CIN + lane * 2;
    unsafeAtomicAdd(a + 0, v.x);
    unsafeAtomicAdd(a + 1, v.y);
    if (lane == 0) unsafeAtomicAdd(cnt + d, 1.0f);
}

// ---------------------------------------------------------------------------
// Edge scatter, C=256: one wave per edge. Lane i handles float4 at col 4*i.
// ---------------------------------------------------------------------------
__global__ __launch_bounds__(256) void scatter_k256(
    const float* __restrict__ h, const int* __restrict__ src,
    const int* __restrict__ dst, float* __restrict__ agg,
    float* __restrict__ cnt)
{
    const int e    = blockIdx.x * 4 + (threadIdx.x >> 6);
    const int lane = threadIdx.x & 63;
    const int s = src[e];
    const int d = dst[e];
    const float4 v = *(const float4*)(h + (size_t)s * HD + lane * 4);
    float* a = agg + (size_t)d * HD + lane * 4;
    unsafeAtomicAdd(a + 0, v.x);
    unsafeAtomicAdd(a + 1, v.y);
    unsafeAtomicAdd(a + 2, v.z);
    unsafeAtomicAdd(a + 3, v.w);
    if (lane == 0) unsafeAtomicAdd(cnt + d, 1.0f);
}

// ---------------------------------------------------------------------------
// Fused:  out[m, :] = act( (agg[m,:]/max(cnt,1)) @ Wl + Xd[m,:] @ Wr + b )
// Tile: 16 rows per block, all 256 cols. 256 threads.
//   thread t: rows r4..r4+3 (r4 = (t>>6)*4), cols col..col+3 (col = (t&63)*4)
// A-tiles stored transposed in LDS -> compute reads are wave-broadcast
// ds_read_b128; W reads are fully-coalesced 1KB/wave L2 hits.
// ---------------------------------------------------------------------------
template<int K, bool RELU>
__global__ __launch_bounds__(256) void sage_gemm(
    const float* __restrict__ A,  const float* __restrict__ cnt,
    const float* __restrict__ Xd,
    const float* __restrict__ Wl, const float* __restrict__ Wr,
    const float* __restrict__ b,  float* __restrict__ outp)
{
    __shared__ float Al[K][16];
    __shared__ float Ar[K][16];

    const int t    = threadIdx.x;
    const int row0 = blockIdx.x * 16;

    // ---- load phase: 16 rows of A (normalized) and Xd, transposed into LDS
    {
        const int r   = t & 15;        // row within tile
        const int c   = t >> 4;        // 0..15 column-chunk
        const int per = K / 16;        // 8 (K=128) or 16 (K=256)
        const int row = row0 + r;
        const float scale = 1.0f / fmaxf(cnt[row], 1.0f);
        const float* arow = A  + (size_t)row * K + c * per;
        const float* xrow = Xd + (size_t)row * K + c * per;
        #pragma unroll
        for (int i = 0; i < per; i += 4) {
            float4 va = *(const float4*)(arow + i);
            float4 vx = *(const float4*)(xrow + i);
            const int k0 = c * per + i;
            Al[k0 + 0][r] = va.x * scale;
            Al[k0 + 1][r] = va.y * scale;
            Al[k0 + 2][r] = va.z * scale;
            Al[k0 + 3][r] = va.w * scale;
            Ar[k0 + 0][r] = vx.x;
            Ar[k0 + 1][r] = vx.y;
            Ar[k0 + 2][r] = vx.z;
            Ar[k0 + 3][r] = vx.w;
        }
    }
    __syncthreads();

    const int lane = t & 63;
    const int r4   = (t >> 6) * 4;
    const int col  = lane * 4;

    float acc[4][4];
    #pragma unroll
    for (int i = 0; i < 4; i++)
        #pragma unroll
        for (int j = 0; j < 4; j++) acc[i][j] = 0.0f;

    auto fma16 = [&](float4 a, float4 w) {
        acc[0][0] += a.x * w.x; acc[0][1] += a.x * w.y;
        acc[0][2] += a.x * w.z; acc[0][3] += a.x * w.w;
        acc[1][0] += a.y * w.x; acc[1][1] += a.y * w.y;
        acc[1][2] += a.y * w.z; acc[1][3] += a.y * w.w;
        acc[2][0] += a.z * w.x; acc[2][1] += a.z * w.y;
        acc[2][2] += a.z * w.z; acc[2][3] += a.z * w.w;
        acc[3][0] += a.w * w.x; acc[3][1] += a.w * w.y;
        acc[3][2] += a.w * w.z; acc[3][3] += a.w * w.w;
    };

    #pragma unroll 4
    for (int k = 0; k < K; k++) {
        float4 a = *(const float4*)&Al[k][r4];
        float4 w = *(const float4*)&Wl[(size_t)k * HD + col];
        fma16(a, w);
    }
    #pragma unroll 4
    for (int k = 0; k < K; k++) {
        float4 a = *(const float4*)&Ar[k][r4];
        float4 w = *(const float4*)&Wr[(size_t)k * HD + col];
        fma16(a, w);
    }

    const float4 bias = *(const float4*)&b[col];
    #pragma unroll
    for (int i = 0; i < 4; i++) {
        float4 o;
        o.x = acc[i][0] + bias.x;
        o.y = acc[i][1] + bias.y;
        o.z = acc[i][2] + bias.z;
        o.w = acc[i][3] + bias.w;
        if (RELU) {
            o.x = fmaxf(o.x, 0.0f);
            o.y = fmaxf(o.y, 0.0f);
            o.z = fmaxf(o.z, 0.0f);
            o.w = fmaxf(o.w, 0.0f);
        }
        *(float4*)&outp[(size_t)(row0 + r4 + i) * HD + col] = o;
    }
}

extern "C" void kernel_launch(void* const* d_in, const int* in_sizes, int n_in,
                              void* d_out, int out_size, void* d_ws, size_t ws_size,
                              hipStream_t stream)
{
    const float* x    = (const float*)d_in[0];
    const int*   src1 = (const int*)  d_in[1];
    const int*   dst1 = (const int*)  d_in[2];
    const int*   src2 = (const int*)  d_in[3];
    const int*   dst2 = (const int*)  d_in[4];
    const float* Wl1  = (const float*)d_in[5];
    const float* Wr1  = (const float*)d_in[6];
    const float* b1   = (const float*)d_in[7];
    const float* Wl2  = (const float*)d_in[8];
    const float* Wr2  = (const float*)d_in[9];
    const float* b2   = (const float*)d_in[10];
    float* out = (float*)d_out;

    // workspace layout (floats): agg1 | cnt1 | agg2 | cnt2 | h
    float* ws0  = (float*)d_ws;
    float* agg1 = ws0;                            // N1*CIN = 6,400,000
    float* cnt1 = agg1 + (size_t)N1 * CIN;        // N1     =    50,000
    float* agg2 = cnt1 + N1;                      // N2*HD  = 2,560,000
    float* cnt2 = agg2 + (size_t)N2 * HD;         // N2     =    10,000
    float* h    = cnt2 + N2;                      // N1*HD  = 12,800,000

    const size_t zero_floats = (size_t)N1 * CIN + N1 + (size_t)N2 * HD + N2;
    hipMemsetAsync(ws0, 0, zero_floats * sizeof(float), stream);

    // layer 1 aggregate: 4 edges per 256-thread block
    scatter_k128<<<E1 / 4, 256, 0, stream>>>(x, src1, dst1, agg1, cnt1);
    // layer 1 transform: h = relu(mean @ Wl1 + x[:N1] @ Wr1 + b1)
    sage_gemm<CIN, true><<<N1 / 16, 256, 0, stream>>>(agg1, cnt1, x, Wl1, Wr1, b1, h);
    // layer 2 aggregate
    scatter_k256<<<E2 / 4, 256, 0, stream>>>(h, src2, dst2, agg2, cnt2);
    // layer 2 transform: out = mean @ Wl2 + h[:N2] @ Wr2 + b2
    sage_gemm<HD, false><<<N2 / 16, 256, 0, stream>>>(agg2, cnt2, h, Wl2, Wr2, b2, out);
}

// Round 2
// 727.705 us; speedup vs baseline: 2.8011x; 2.8011x over previous
//
#include <hip/hip_runtime.h>

#define N0 200000
#define N1 50000
#define N2 10000
#define E1 1000000
#define E2 250000
#define CIN 128
#define HD  256

// ---------------------------------------------------------------------------
// Histogram: deg[dst[e]]++ over E edges.
// ---------------------------------------------------------------------------
__global__ __launch_bounds__(256) void hist_kernel(
    const int* __restrict__ dst, int* __restrict__ deg, int E)
{
    const int e = blockIdx.x * 256 + threadIdx.x;
    if (e < E) atomicAdd(&deg[dst[e]], 1);
}

// ---------------------------------------------------------------------------
// Single-block exclusive scan of deg[0..n) -> off[0..n], and cur = off copy.
// Two-phase: per-thread chunk sums, LDS scan of 1024 partials, rewrite pass.
// ---------------------------------------------------------------------------
__global__ __launch_bounds__(1024) void exscan_kernel(
    const int* __restrict__ deg, int* __restrict__ off,
    int* __restrict__ cur, int n)
{
    __shared__ int partial[1024];
    const int t = threadIdx.x;
    const int chunk = (n + 1023) / 1024;
    const int lo = t * chunk;
    const int hi = min(lo + chunk, n);

    int sum = 0;
    for (int i = lo; i < hi; i++) sum += deg[i];
    partial[t] = sum;
    __syncthreads();

    for (int ofs = 1; ofs < 1024; ofs <<= 1) {
        int v = (t >= ofs) ? partial[t - ofs] : 0;
        __syncthreads();
        partial[t] += v;
        __syncthreads();
    }

    int run = partial[t] - sum;   // exclusive prefix of this thread's chunk
    for (int i = lo; i < hi; i++) {
        int d = deg[i];
        off[i] = run;
        cur[i] = run;
        run += d;
    }
    if (t == 1023) off[n] = partial[1023];
}

// ---------------------------------------------------------------------------
// Fill: for each edge, claim a slot in its dst bucket and store the SRC id.
// ---------------------------------------------------------------------------
__global__ __launch_bounds__(256) void fill_kernel(
    const int* __restrict__ src, const int* __restrict__ dst,
    int* __restrict__ cur, int* __restrict__ eid, int E)
{
    const int e = blockIdx.x * 256 + threadIdx.x;
    if (e < E) {
        const int p = atomicAdd(&cur[dst[e]], 1);
        eid[p] = src[e];
    }
}

// ---------------------------------------------------------------------------
// Gather-mean, C=128: one wave per dst row. Half-waves (32 lanes x float4 =
// 128 cols) process alternating edges; combine with shfl_xor(32).
// Writes the NORMALIZED mean row.
// ---------------------------------------------------------------------------
__global__ __launch_bounds__(256) void gather_k128(
    const float* __restrict__ x, const int* __restrict__ eid,
    const int* __restrict__ off, float* __restrict__ agg)
{
    const int w = blockIdx.x * 4 + (threadIdx.x >> 6);   // dst row
    const int lane = threadIdx.x & 63;
    const int half = lane >> 5;
    const int l32  = lane & 31;
    const int base = off[w];
    const int n    = off[w + 1] - base;

    float4 acc = {0.f, 0.f, 0.f, 0.f};
    for (int i = half; i < n; i += 2) {
        const int s = eid[base + i];
        const float4 v = *(const float4*)(x + (size_t)s * CIN + l32 * 4);
        acc.x += v.x; acc.y += v.y; acc.z += v.z; acc.w += v.w;
    }
    acc.x += __shfl_xor(acc.x, 32);
    acc.y += __shfl_xor(acc.y, 32);
    acc.z += __shfl_xor(acc.z, 32);
    acc.w += __shfl_xor(acc.w, 32);

    if (half == 0) {
        const float s = 1.0f / fmaxf((float)n, 1.0f);
        acc.x *= s; acc.y *= s; acc.z *= s; acc.w *= s;
        *(float4*)(agg + (size_t)w * CIN + l32 * 4) = acc;
    }
}

// ---------------------------------------------------------------------------
// Gather-mean, C=256: one wave per dst row, float4 per lane.
// ---------------------------------------------------------------------------
__global__ __launch_bounds__(256) void gather_k256(
    const float* __restrict__ h, const int* __restrict__ eid,
    const int* __restrict__ off, float* __restrict__ agg)
{
    const int w = blockIdx.x * 4 + (threadIdx.x >> 6);
    const int lane = threadIdx.x & 63;
    const int base = off[w];
    const int n    = off[w + 1] - base;

    float4 acc = {0.f, 0.f, 0.f, 0.f};
    for (int i = 0; i < n; i++) {
        const int s = eid[base + i];
        const float4 v = *(const float4*)(h + (size_t)s * HD + lane * 4);
        acc.x += v.x; acc.y += v.y; acc.z += v.z; acc.w += v.w;
    }
    const float s = 1.0f / fmaxf((float)n, 1.0f);
    acc.x *= s; acc.y *= s; acc.z *= s; acc.w *= s;
    *(float4*)(agg + (size_t)w * HD + lane * 4) = acc;
}

// ---------------------------------------------------------------------------
// Fused:  out[m, :] = act( agg[m,:] @ Wl + Xd[m,:] @ Wr + b )
// agg is pre-normalized. 16 rows/block, 256 cols, 256 threads.
// A-tiles transposed in LDS -> broadcast ds_read_b128; W reads L2-hit 1KB/wave.
// ---------------------------------------------------------------------------
template<int K, bool RELU>
__global__ __launch_bounds__(256) void sage_gemm(
    const float* __restrict__ A,  const float* __restrict__ Xd,
    const float* __restrict__ Wl, const float* __restrict__ Wr,
    const float* __restrict__ b,  float* __restrict__ outp)
{
    __shared__ float Al[K][16];
    __shared__ float Ar[K][16];

    const int t    = threadIdx.x;
    const int row0 = blockIdx.x * 16;

    {
        const int r   = t & 15;
        const int c   = t >> 4;
        const int per = K / 16;
        const int row = row0 + r;
        const float* arow = A  + (size_t)row * K + c * per;
        const float* xrow = Xd + (size_t)row * K + c * per;
        #pragma unroll
        for (int i = 0; i < per; i += 4) {
            float4 va = *(const float4*)(arow + i);
            float4 vx = *(const float4*)(xrow + i);
            const int k0 = c * per + i;
            Al[k0 + 0][r] = va.x; Al[k0 + 1][r] = va.y;
            Al[k0 + 2][r] = va.z; Al[k0 + 3][r] = va.w;
            Ar[k0 + 0][r] = vx.x; Ar[k0 + 1][r] = vx.y;
            Ar[k0 + 2][r] = vx.z; Ar[k0 + 3][r] = vx.w;
        }
    }
    __syncthreads();

    const int lane = t & 63;
    const int r4   = (t >> 6) * 4;
    const int col  = lane * 4;

    float acc[4][4];
    #pragma unroll
    for (int i = 0; i < 4; i++)
        #pragma unroll
        for (int j = 0; j < 4; j++) acc[i][j] = 0.0f;

    auto fma16 = [&](float4 a, float4 w) {
        acc[0][0] += a.x * w.x; acc[0][1] += a.x * w.y;
        acc[0][2] += a.x * w.z; acc[0][3] += a.x * w.w;
        acc[1][0] += a.y * w.x; acc[1][1] += a.y * w.y;
        acc[1][2] += a.y * w.z; acc[1][3] += a.y * w.w;
        acc[2][0] += a.z * w.x; acc[2][1] += a.z * w.y;
        acc[2][2] += a.z * w.z; acc[2][3] += a.z * w.w;
        acc[3][0] += a.w * w.x; acc[3][1] += a.w * w.y;
        acc[3][2] += a.w * w.z; acc[3][3] += a.w * w.w;
    };

    #pragma unroll 4
    for (int k = 0; k < K; k++) {
        float4 a = *(const float4*)&Al[k][r4];
        float4 w = *(const float4*)&Wl[(size_t)k * HD + col];
        fma16(a, w);
    }
    #pragma unroll 4
    for (int k = 0; k < K; k++) {
        float4 a = *(const float4*)&Ar[k][r4];
        float4 w = *(const float4*)&Wr[(size_t)k * HD + col];
        fma16(a, w);
    }

    const float4 bias = *(const float4*)&b[col];
    #pragma unroll
    for (int i = 0; i < 4; i++) {
        float4 o;
        o.x = acc[i][0] + bias.x;
        o.y = acc[i][1] + bias.y;
        o.z = acc[i][2] + bias.z;
        o.w = acc[i][3] + bias.w;
        if (RELU) {
            o.x = fmaxf(o.x, 0.0f);
            o.y = fmaxf(o.y, 0.0f);
            o.z = fmaxf(o.z, 0.0f);
            o.w = fmaxf(o.w, 0.0f);
        }
        *(float4*)&outp[(size_t)(row0 + r4 + i) * HD + col] = o;
    }
}

extern "C" void kernel_launch(void* const* d_in, const int* in_sizes, int n_in,
                              void* d_out, int out_size, void* d_ws, size_t ws_size,
                              hipStream_t stream)
{
    const float* x    = (const float*)d_in[0];
    const int*   src1 = (const int*)  d_in[1];
    const int*   dst1 = (const int*)  d_in[2];
    const int*   src2 = (const int*)  d_in[3];
    const int*   dst2 = (const int*)  d_in[4];
    const float* Wl1  = (const float*)d_in[5];
    const float* Wr1  = (const float*)d_in[6];
    const float* b1   = (const float*)d_in[7];
    const float* Wl2  = (const float*)d_in[8];
    const float* Wr2  = (const float*)d_in[9];
    const float* b2   = (const float*)d_in[10];
    float* out = (float*)d_out;

    // ---- workspace layout (floats), with CSR scratch aliased into dead
    //      regions so total = 87.04 MB:
    //   agg1: [0, 6.4M)      — live from gather1 until gemm1
    //   agg2: [6.4M, 8.96M)  — live from gather2 until gemm2
    //   h:    [8.96M, 21.76M)— live from gemm1 until gemm2
    float* agg1 = (float*)d_ws;
    float* agg2 = agg1 + (size_t)N1 * CIN;
    float* h    = agg2 + (size_t)N2 * HD;

    // Layer-1 CSR lives inside agg2 (agg2 first written by gather2, which is
    // after every consumer of these arrays):
    int* deg1 = (int*)agg2;          // 50,000
    int* cur1 = deg1 + N1;           // 50,000
    int* off1 = cur1 + N1;           // 50,001
    int* eid1 = off1 + N1 + 1;       // 1,000,000   (total 4.6 MB <= 10.24 MB)

    // Layer-2 CSR lives inside agg1 (agg1 dead after gemm1; these arrays are
    // only written/read after gemm1):
    int* deg2 = (int*)agg1;          // 10,000
    int* cur2 = deg2 + N2;           // 10,000
    int* off2 = cur2 + N2;           // 10,001
    int* eid2 = off2 + N2 + 1;       // 250,000    (total 1.1 MB <= 25.6 MB)

    // ---------------- layer 1 ----------------
    hipMemsetAsync(deg1, 0, (size_t)N1 * sizeof(int), stream);
    hist_kernel<<<(E1 + 255) / 256, 256, 0, stream>>>(dst1, deg1, E1);
    exscan_kernel<<<1, 1024, 0, stream>>>(deg1, off1, cur1, N1);
    fill_kernel<<<(E1 + 255) / 256, 256, 0, stream>>>(src1, dst1, cur1, eid1, E1);
    gather_k128<<<N1 / 4, 256, 0, stream>>>(x, eid1, off1, agg1);
    sage_gemm<CIN, true><<<N1 / 16, 256, 0, stream>>>(agg1, x, Wl1, Wr1, b1, h);

    // ---------------- layer 2 ----------------
    hipMemsetAsync(deg2, 0, (size_t)N2 * sizeof(int), stream);
    hist_kernel<<<(E2 + 255) / 256, 256, 0, stream>>>(dst2, deg2, E2);
    exscan_kernel<<<1, 1024, 0, stream>>>(deg2, off2, cur2, N2);
    fill_kernel<<<(E2 + 255) / 256, 256, 0, stream>>>(src2, dst2, cur2, eid2, E2);
    gather_k256<<<N2 / 4, 256, 0, stream>>>(h, eid2, off2, agg2);
    sage_gemm<HD, false><<<N2 / 16, 256, 0, stream>>>(agg2, h, Wl2, Wr2, b2, out);
}

// Round 3
// 584.617 us; speedup vs baseline: 3.4867x; 1.2448x over previous
//
#include <hip/hip_runtime.h>

#define N0 200000
#define N1 50000
#define N2 10000
#define E1 1000000
#define E2 250000
#define CIN 128
#define HD  256

typedef __attribute__((ext_vector_type(8))) short short8;   // 8 bf16 = 4 VGPR
typedef __attribute__((ext_vector_type(4))) float f32x4;    // MFMA acc

__device__ __forceinline__ unsigned short f2bf(float f) {
    unsigned u = __builtin_bit_cast(unsigned, f);
    u = (u + 0x7fffu + ((u >> 16) & 1u)) >> 16;   // RNE
    return (unsigned short)u;
}
__device__ __forceinline__ float bf2f(unsigned short h) {
    unsigned u = ((unsigned)h) << 16;
    return __builtin_bit_cast(float, u);
}

// ---------------------------------------------------------------------------
// fp32 -> bf16 bulk convert (float4 -> ushort4 per thread)
// ---------------------------------------------------------------------------
__global__ __launch_bounds__(256) void cvt_x_kernel(
    const float* __restrict__ x, unsigned short* __restrict__ xb, int n4)
{
    const int i = blockIdx.x * 256 + threadIdx.x;
    if (i >= n4) return;
    const float4 v = ((const float4*)x)[i];
    ushort4 o;
    o.x = f2bf(v.x); o.y = f2bf(v.y); o.z = f2bf(v.z); o.w = f2bf(v.w);
    ((ushort4*)xb)[i] = o;
}

// ---------------------------------------------------------------------------
// Build swizzled bf16 B-operand buffer for [Wl ; Wr] (Kcat = 2K rows, 256 cols).
// Fragment order: Wsw[kt][nt][lane][j]  (j=0..7),
//   element = Wcat[k = kt*32 + (lane>>4)*8 + j][n = nt*16 + (lane&15)]
// One thread per bf16 element; total = 2K*256.
// ---------------------------------------------------------------------------
__global__ __launch_bounds__(256) void cvt_w_kernel(
    const float* __restrict__ Wl, const float* __restrict__ Wr,
    unsigned short* __restrict__ wsw, int K)
{
    const int tid = blockIdx.x * 256 + threadIdx.x;
    const int j  = tid & 7;
    const int L  = (tid >> 3) & 63;
    const int nt = (tid >> 9) & 15;
    const int kt = tid >> 13;
    const int k  = kt * 32 + (L >> 4) * 8 + j;
    const int n  = nt * 16 + (L & 15);
    const float v = (k < K) ? Wl[(size_t)k * HD + n] : Wr[(size_t)(k - K) * HD + n];
    wsw[tid] = f2bf(v);
}

// ---------------------------------------------------------------------------
// CSR build: histogram, single-block exclusive scan, slot fill.
// ---------------------------------------------------------------------------
__global__ __launch_bounds__(256) void hist_kernel(
    const int* __restrict__ dst, int* __restrict__ deg, int E)
{
    const int e = blockIdx.x * 256 + threadIdx.x;
    if (e < E) atomicAdd(&deg[dst[e]], 1);
}

__global__ __launch_bounds__(1024) void exscan_kernel(
    const int* __restrict__ deg, int* __restrict__ off,
    int* __restrict__ cur, int n)
{
    __shared__ int partial[1024];
    const int t = threadIdx.x;
    const int chunk = (n + 1023) / 1024;
    const int lo = t * chunk;
    const int hi = min(lo + chunk, n);

    int sum = 0;
    for (int i = lo; i < hi; i++) sum += deg[i];
    partial[t] = sum;
    __syncthreads();

    for (int ofs = 1; ofs < 1024; ofs <<= 1) {
        int v = (t >= ofs) ? partial[t - ofs] : 0;
        __syncthreads();
        partial[t] += v;
        __syncthreads();
    }

    int run = partial[t] - sum;
    for (int i = lo; i < hi; i++) {
        int d = deg[i];
        off[i] = run;
        cur[i] = run;
        run += d;
    }
    if (t == 1023) off[n] = partial[1023];
}

__global__ __launch_bounds__(256) void fill_kernel(
    const int* __restrict__ src, const int* __restrict__ dst,
    int* __restrict__ cur, int* __restrict__ eid, int E)
{
    const int e = blockIdx.x * 256 + threadIdx.x;
    if (e < E) {
        const int p = atomicAdd(&cur[dst[e]], 1);
        eid[p] = src[e];
    }
}

// ---------------------------------------------------------------------------
// Gather-mean C=128 (bf16 in/out): one wave per dst row; two 32-lane halves
// process alternating edges (32 lanes x 4 bf16 = 256B row); fp32 accumulate;
// combine via shfl_xor(32); write normalized bf16 row.
// ---------------------------------------------------------------------------
__global__ __launch_bounds__(256) void gather_k128b(
    const unsigned short* __restrict__ xb, const int* __restrict__ eid,
    const int* __restrict__ off, unsigned short* __restrict__ agg)
{
    const int w = blockIdx.x * 4 + (threadIdx.x >> 6);
    const int lane = threadIdx.x & 63;
    const int half = lane >> 5;
    const int l32  = lane & 31;
    const int base = off[w];
    const int n    = off[w + 1] - base;

    float ax = 0.f, ay = 0.f, az = 0.f, aw = 0.f;
    for (int i = half; i < n; i += 2) {
        const int s = eid[base + i];
        const ushort4 v = *(const ushort4*)(xb + (size_t)s * CIN + l32 * 4);
        ax += bf2f(v.x); ay += bf2f(v.y); az += bf2f(v.z); aw += bf2f(v.w);
    }
    ax += __shfl_xor(ax, 32);
    ay += __shfl_xor(ay, 32);
    az += __shfl_xor(az, 32);
    aw += __shfl_xor(aw, 32);

    if (half == 0) {
        const float s = 1.0f / fmaxf((float)n, 1.0f);
        ushort4 o;
        o.x = f2bf(ax * s); o.y = f2bf(ay * s);
        o.z = f2bf(az * s); o.w = f2bf(aw * s);
        *(ushort4*)(agg + (size_t)w * CIN + l32 * 4) = o;
    }
}

// ---------------------------------------------------------------------------
// Gather-mean C=256 (bf16 in/out): one wave per dst row (64 lanes x 4 bf16).
// ---------------------------------------------------------------------------
__global__ __launch_bounds__(256) void gather_k256b(
    const unsigned short* __restrict__ hb, const int* __restrict__ eid,
    const int* __restrict__ off, unsigned short* __restrict__ agg)
{
    const int w = blockIdx.x * 4 + (threadIdx.x >> 6);
    const int lane = threadIdx.x & 63;
    const int base = off[w];
    const int n    = off[w + 1] - base;

    float ax = 0.f, ay = 0.f, az = 0.f, aw = 0.f;
    for (int i = 0; i < n; i++) {
        const int s = eid[base + i];
        const ushort4 v = *(const ushort4*)(hb + (size_t)s * HD + lane * 4);
        ax += bf2f(v.x); ay += bf2f(v.y); az += bf2f(v.z); aw += bf2f(v.w);
    }
    const float s = 1.0f / fmaxf((float)n, 1.0f);
    ushort4 o;
    o.x = f2bf(ax * s); o.y = f2bf(ay * s);
    o.z = f2bf(az * s); o.w = f2bf(aw * s);
    *(ushort4*)(agg + (size_t)w * HD + lane * 4) = o;
}

// ---------------------------------------------------------------------------
// MFMA GEMM:  out[m,:256] = act( [A1 | A2][m,:] @ Wsw + b )
// A1: [M][K1] bf16 (pre-normalized agg), A2: [M][K2] bf16 (dst features).
// Block = 256 thr = 4 waves; tile = 16 rows x 256 cols; wave w owns n-tiles
// 4w..4w+3. LDS-free: A-frags direct global (16B/lane), B-frags from the
// pre-swizzled Wsw (coalesced 1KB/wave, L2-resident).
// Frag layouts (m89/m91-verified): A[m=lane&15][k=(lane>>4)*8+j],
// B[k=(lane>>4)*8+j][n=lane&15], D col=lane&15, row=(lane>>4)*4+reg.
// ---------------------------------------------------------------------------
template<int K1, int K2, bool RELU, bool OUTBF>
__global__ __launch_bounds__(256) void mfma_gemm(
    const unsigned short* __restrict__ A1, const unsigned short* __restrict__ A2,
    const unsigned short* __restrict__ wsw, const float* __restrict__ bias,
    void* __restrict__ outp)
{
    constexpr int KT1 = K1 / 32;
    constexpr int KT  = (K1 + K2) / 32;

    const int t = threadIdx.x;
    const int w = t >> 6;
    const int L = t & 63;
    const int m = L & 15;
    const int q = L >> 4;
    const int row0 = blockIdx.x * 16;

    const unsigned short* a1p = A1 + (size_t)(row0 + m) * K1 + q * 8;
    const unsigned short* a2p = A2 + (size_t)(row0 + m) * K2 + q * 8;

    f32x4 acc[4] = {{0.f,0.f,0.f,0.f},{0.f,0.f,0.f,0.f},
                    {0.f,0.f,0.f,0.f},{0.f,0.f,0.f,0.f}};

    #pragma unroll
    for (int kt = 0; kt < KT; kt++) {
        short8 af;
        if (kt < KT1) af = *(const short8*)(a1p + kt * 32);
        else          af = *(const short8*)(a2p + (kt - KT1) * 32);
        #pragma unroll
        for (int tt = 0; tt < 4; tt++) {
            const short8 bf = *(const short8*)(
                wsw + (((size_t)kt * 16 + (w * 4 + tt)) * 64 + L) * 8);
            acc[tt] = __builtin_amdgcn_mfma_f32_16x16x32_bf16(af, bf, acc[tt], 0, 0, 0);
        }
    }

    const int orow = row0 + q * 4;
    #pragma unroll
    for (int tt = 0; tt < 4; tt++) {
        const int col = (w * 4 + tt) * 16 + m;
        const float bv = bias[col];
        #pragma unroll
        for (int r = 0; r < 4; r++) {
            float v = acc[tt][r] + bv;
            if (RELU) v = fmaxf(v, 0.0f);
            const size_t idx = (size_t)(orow + r) * HD + col;
            if (OUTBF) ((unsigned short*)outp)[idx] = f2bf(v);
            else       ((float*)outp)[idx] = v;
        }
    }
}

extern "C" void kernel_launch(void* const* d_in, const int* in_sizes, int n_in,
                              void* d_out, int out_size, void* d_ws, size_t ws_size,
                              hipStream_t stream)
{
    const float* x    = (const float*)d_in[0];
    const int*   src1 = (const int*)  d_in[1];
    const int*   dst1 = (const int*)  d_in[2];
    const int*   src2 = (const int*)  d_in[3];
    const int*   dst2 = (const int*)  d_in[4];
    const float* Wl1  = (const float*)d_in[5];
    const float* Wr1  = (const float*)d_in[6];
    const float* b1   = (const float*)d_in[7];
    const float* Wl2  = (const float*)d_in[8];
    const float* Wr2  = (const float*)d_in[9];
    const float* b2   = (const float*)d_in[10];
    float* out = (float*)d_out;

    // ---- workspace layout (bf16 elements unless noted), ~69.5 MB total:
    //  xb   [N0*128]  51.2MB — bf16 copy of x; tail rows >= N1 reused for hb
    //  agg1 [N1*128]  12.8MB — layer-1 mean (bf16); CSR2 aliased here later
    //  agg2 [N2*256]  5.12MB — layer-2 mean (bf16); CSR1 aliased here earlier
    //  wsw1 [256*256] 131KB  — swizzled [Wl1;Wr1]
    //  wsw2 [512*256] 262KB  — swizzled [Wl2;Wr2]
    unsigned short* xb   = (unsigned short*)d_ws;
    unsigned short* hb   = xb + (size_t)N1 * CIN;          // h rows alias xb rows>=N1
    unsigned short* agg1 = xb + (size_t)N0 * CIN;
    unsigned short* agg2 = agg1 + (size_t)N1 * CIN;
    unsigned short* wsw1 = agg2 + (size_t)N2 * HD;
    unsigned short* wsw2 = wsw1 + 2 * CIN * HD;

    // CSR1 aliased into agg2's region (agg2 first written by gather2, after
    // all CSR1 consumers):  needs 4.6MB <= 5.12MB
    int* deg1 = (int*)agg2;
    int* cur1 = deg1 + N1;
    int* off1 = cur1 + N1;
    int* eid1 = off1 + N1 + 1;
    // CSR2 aliased into agg1's region (agg1 dead after gemm1): 1.12MB <= 12.8MB
    int* deg2 = (int*)agg1;
    int* cur2 = deg2 + N2;
    int* off2 = cur2 + N2;
    int* eid2 = off2 + N2 + 1;

    // ---- dtype prep
    cvt_x_kernel<<<(N0 * CIN / 4 + 255) / 256, 256, 0, stream>>>(x, xb, N0 * CIN / 4);
    cvt_w_kernel<<<(2 * CIN * HD) / 256, 256, 0, stream>>>(Wl1, Wr1, wsw1, CIN);
    cvt_w_kernel<<<(2 * HD * HD) / 256, 256, 0, stream>>>(Wl2, Wr2, wsw2, HD);

    // ---- layer 1
    hipMemsetAsync(deg1, 0, (size_t)N1 * sizeof(int), stream);
    hist_kernel<<<(E1 + 255) / 256, 256, 0, stream>>>(dst1, deg1, E1);
    exscan_kernel<<<1, 1024, 0, stream>>>(deg1, off1, cur1, N1);
    fill_kernel<<<(E1 + 255) / 256, 256, 0, stream>>>(src1, dst1, cur1, eid1, E1);
    gather_k128b<<<N1 / 4, 256, 0, stream>>>(xb, eid1, off1, agg1);
    mfma_gemm<CIN, CIN, true, true><<<N1 / 16, 256, 0, stream>>>(agg1, xb, wsw1, b1, hb);

    // ---- layer 2
    hipMemsetAsync(deg2, 0, (size_t)N2 * sizeof(int), stream);
    hist_kernel<<<(E2 + 255) / 256, 256, 0, stream>>>(dst2, deg2, E2);
    exscan_kernel<<<1, 1024, 0, stream>>>(deg2, off2, cur2, N2);
    fill_kernel<<<(E2 + 255) / 256, 256, 0, stream>>>(src2, dst2, cur2, eid2, E2);
    gather_k256b<<<N2 / 4, 256, 0, stream>>>(hb, eid2, off2, agg2);
    mfma_gemm<HD, HD, false, false><<<N2 / 16, 256, 0, stream>>>(agg2, hb, wsw2, b2, out);
}

// Round 4
// 485.492 us; speedup vs baseline: 4.1986x; 1.2042x over previous
//
#include <hip/hip_runtime.h>

#define N0 200000
#define N1 50000
#define N2 10000
#define E1 1000000
#define E2 250000
#define CIN 128
#define HD  256

typedef __attribute__((ext_vector_type(8))) short short8;   // 8 bf16 = 4 VGPR
typedef __attribute__((ext_vector_type(4))) float f32x4;    // MFMA acc

__device__ __forceinline__ unsigned short f2bf(float f) {
    unsigned u = __builtin_bit_cast(unsigned, f);
    u = (u + 0x7fffu + ((u >> 16) & 1u)) >> 16;   // RNE
    return (unsigned short)u;
}
__device__ __forceinline__ float bf2f(unsigned short h) {
    unsigned u = ((unsigned)h) << 16;
    return __builtin_bit_cast(float, u);
}

// ---------------------------------------------------------------------------
// fp32 -> bf16 bulk convert (float4 -> ushort4 per thread)
// ---------------------------------------------------------------------------
__global__ __launch_bounds__(256) void cvt_x_kernel(
    const float* __restrict__ x, unsigned short* __restrict__ xb, int n4)
{
    const int i = blockIdx.x * 256 + threadIdx.x;
    if (i >= n4) return;
    const float4 v = ((const float4*)x)[i];
    ushort4 o;
    o.x = f2bf(v.x); o.y = f2bf(v.y); o.z = f2bf(v.z); o.w = f2bf(v.w);
    ((ushort4*)xb)[i] = o;
}

// ---------------------------------------------------------------------------
// Build swizzled bf16 B-operand buffer for [Wl ; Wr] (Kcat = 2K rows, 256 cols).
// Wsw[kt][nt][lane][j] = Wcat[kt*32 + (lane>>4)*8 + j][nt*16 + (lane&15)]
// ---------------------------------------------------------------------------
__global__ __launch_bounds__(256) void cvt_w_kernel(
    const float* __restrict__ Wl, const float* __restrict__ Wr,
    unsigned short* __restrict__ wsw, int K)
{
    const int tid = blockIdx.x * 256 + threadIdx.x;
    const int j  = tid & 7;
    const int L  = (tid >> 3) & 63;
    const int nt = (tid >> 9) & 15;
    const int kt = tid >> 13;
    const int k  = kt * 32 + (L >> 4) * 8 + j;
    const int n  = nt * 16 + (L & 15);
    const float v = (k < K) ? Wl[(size_t)k * HD + n] : Wr[(size_t)(k - K) * HD + n];
    wsw[tid] = f2bf(v);
}

// ---------------------------------------------------------------------------
// CSR build: histogram + hierarchical exclusive scan + slot fill.
// ---------------------------------------------------------------------------
__global__ __launch_bounds__(256) void hist_kernel(
    const int* __restrict__ dst, int* __restrict__ deg, int E)
{
    const int e = blockIdx.x * 256 + threadIdx.x;
    if (e < E) atomicAdd(&deg[dst[e]], 1);
}

// Phase 1: per-1024-tile sums (256 thr x int4). n % 4 == 0 guaranteed.
__global__ __launch_bounds__(256) void scan_partial(
    const int* __restrict__ deg, int* __restrict__ tilesum, int n)
{
    const int t = threadIdx.x;
    const int pos = blockIdx.x * 1024 + t * 4;
    int s = 0;
    if (pos < n) {
        const int4 v = *(const int4*)(deg + pos);
        s = v.x + v.y + v.z + v.w;
    }
    __shared__ int red[256];
    red[t] = s;
    __syncthreads();
    #pragma unroll
    for (int ofs = 128; ofs > 0; ofs >>= 1) {
        if (t < ofs) red[t] += red[t + ofs];
        __syncthreads();
    }
    if (t == 0) tilesum[blockIdx.x] = red[0];
}

// Phase 2: single-wave in-register exclusive scan of <=64 tile sums.
__global__ __launch_bounds__(64) void scan_tiles(
    int* __restrict__ tilesum, int ntiles)
{
    const int t = threadIdx.x;
    const int orig = (t < ntiles) ? tilesum[t] : 0;
    int v = orig;
    #pragma unroll
    for (int ofs = 1; ofs < 64; ofs <<= 1) {
        const int u = __shfl_up(v, ofs);
        if (t >= ofs) v += u;
    }
    if (t < ntiles) tilesum[t] = v - orig;   // exclusive
}

// Phase 3: per-tile exclusive scan + tile offset; writes off and cur.
__global__ __launch_bounds__(256) void scan_final(
    const int* __restrict__ deg, const int* __restrict__ tileoff,
    int* __restrict__ off, int* __restrict__ cur, int n, int E)
{
    const int t = threadIdx.x;
    const int pos = blockIdx.x * 1024 + t * 4;
    int4 v = {0, 0, 0, 0};
    if (pos < n) v = *(const int4*)(deg + pos);
    const int s = v.x + v.y + v.z + v.w;

    __shared__ int red[256];
    red[t] = s;
    __syncthreads();
    #pragma unroll
    for (int ofs = 1; ofs < 256; ofs <<= 1) {
        const int u = (t >= ofs) ? red[t - ofs] : 0;
        __syncthreads();
        red[t] += u;
        __syncthreads();
    }

    if (pos < n) {
        const int base = tileoff[blockIdx.x] + red[t] - s;  // exclusive prefix
        int4 o;
        o.x = base;
        o.y = base + v.x;
        o.z = o.y + v.y;
        o.w = o.z + v.z;
        *(int4*)(off + pos) = o;
        *(int4*)(cur + pos) = o;
    }
    if (blockIdx.x == 0 && t == 0) off[n] = E;
}

__global__ __launch_bounds__(256) void fill_kernel(
    const int* __restrict__ src, const int* __restrict__ dst,
    int* __restrict__ cur, int* __restrict__ eid, int E)
{
    const int e = blockIdx.x * 256 + threadIdx.x;
    if (e < E) {
        const int p = atomicAdd(&cur[dst[e]], 1);
        eid[p] = src[e];
    }
}

// ---------------------------------------------------------------------------
// Gather-mean C=128 (bf16 in/out): one wave per dst row; two 32-lane halves
// process alternating edges; fp32 accumulate; combine via shfl_xor(32).
// ---------------------------------------------------------------------------
__global__ __launch_bounds__(256) void gather_k128b(
    const unsigned short* __restrict__ xb, const int* __restrict__ eid,
    const int* __restrict__ off, unsigned short* __restrict__ agg)
{
    const int w = blockIdx.x * 4 + (threadIdx.x >> 6);
    const int lane = threadIdx.x & 63;
    const int half = lane >> 5;
    const int l32  = lane & 31;
    const int base = off[w];
    const int n    = off[w + 1] - base;

    float ax = 0.f, ay = 0.f, az = 0.f, aw = 0.f;
    for (int i = half; i < n; i += 2) {
        const int s = eid[base + i];
        const ushort4 v = *(const ushort4*)(xb + (size_t)s * CIN + l32 * 4);
        ax += bf2f(v.x); ay += bf2f(v.y); az += bf2f(v.z); aw += bf2f(v.w);
    }
    ax += __shfl_xor(ax, 32);
    ay += __shfl_xor(ay, 32);
    az += __shfl_xor(az, 32);
    aw += __shfl_xor(aw, 32);

    if (half == 0) {
        const float s = 1.0f / fmaxf((float)n, 1.0f);
        ushort4 o;
        o.x = f2bf(ax * s); o.y = f2bf(ay * s);
        o.z = f2bf(az * s); o.w = f2bf(aw * s);
        *(ushort4*)(agg + (size_t)w * CIN + l32 * 4) = o;
    }
}

// ---------------------------------------------------------------------------
// Gather-mean C=256 (bf16 in/out): one wave per dst row.
// ---------------------------------------------------------------------------
__global__ __launch_bounds__(256) void gather_k256b(
    const unsigned short* __restrict__ hb, const int* __restrict__ eid,
    const int* __restrict__ off, unsigned short* __restrict__ agg)
{
    const int w = blockIdx.x * 4 + (threadIdx.x >> 6);
    const int lane = threadIdx.x & 63;
    const int base = off[w];
    const int n    = off[w + 1] - base;

    float ax = 0.f, ay = 0.f, az = 0.f, aw = 0.f;
    for (int i = 0; i < n; i++) {
        const int s = eid[base + i];
        const ushort4 v = *(const ushort4*)(hb + (size_t)s * HD + lane * 4);
        ax += bf2f(v.x); ay += bf2f(v.y); az += bf2f(v.z); aw += bf2f(v.w);
    }
    const float s = 1.0f / fmaxf((float)n, 1.0f);
    ushort4 o;
    o.x = f2bf(ax * s); o.y = f2bf(ay * s);
    o.z = f2bf(az * s); o.w = f2bf(aw * s);
    *(ushort4*)(agg + (size_t)w * HD + lane * 4) = o;
}

// ---------------------------------------------------------------------------
// MFMA GEMM:  out[m,:256] = act( [A1 | A2][m,:] @ Wsw + b )
// 16 rows/block, 4 waves x 4 n-tiles, LDS-free; B from pre-swizzled Wsw.
// ---------------------------------------------------------------------------
template<int K1, int K2, bool RELU, bool OUTBF>
__global__ __launch_bounds__(256) void mfma_gemm(
    const unsigned short* __restrict__ A1, const unsigned short* __restrict__ A2,
    const unsigned short* __restrict__ wsw, const float* __restrict__ bias,
    void* __restrict__ outp)
{
    constexpr int KT1 = K1 / 32;
    constexpr int KT  = (K1 + K2) / 32;

    const int t = threadIdx.x;
    const int w = t >> 6;
    const int L = t & 63;
    const int m = L & 15;
    const int q = L >> 4;
    const int row0 = blockIdx.x * 16;

    const unsigned short* a1p = A1 + (size_t)(row0 + m) * K1 + q * 8;
    const unsigned short* a2p = A2 + (size_t)(row0 + m) * K2 + q * 8;

    f32x4 acc[4] = {{0.f,0.f,0.f,0.f},{0.f,0.f,0.f,0.f},
                    {0.f,0.f,0.f,0.f},{0.f,0.f,0.f,0.f}};

    #pragma unroll
    for (int kt = 0; kt < KT; kt++) {
        short8 af;
        if (kt < KT1) af = *(const short8*)(a1p + kt * 32);
        else          af = *(const short8*)(a2p + (kt - KT1) * 32);
        #pragma unroll
        for (int tt = 0; tt < 4; tt++) {
            const short8 bf = *(const short8*)(
                wsw + (((size_t)kt * 16 + (w * 4 + tt)) * 64 + L) * 8);
            acc[tt] = __builtin_amdgcn_mfma_f32_16x16x32_bf16(af, bf, acc[tt], 0, 0, 0);
        }
    }

    const int orow = row0 + q * 4;
    #pragma unroll
    for (int tt = 0; tt < 4; tt++) {
        const int col = (w * 4 + tt) * 16 + m;
        const float bv = bias[col];
        #pragma unroll
        for (int r = 0; r < 4; r++) {
            float v = acc[tt][r] + bv;
            if (RELU) v = fmaxf(v, 0.0f);
            const size_t idx = (size_t)(orow + r) * HD + col;
            if (OUTBF) ((unsigned short*)outp)[idx] = f2bf(v);
            else       ((float*)outp)[idx] = v;
        }
    }
}

extern "C" void kernel_launch(void* const* d_in, const int* in_sizes, int n_in,
                              void* d_out, int out_size, void* d_ws, size_t ws_size,
                              hipStream_t stream)
{
    const float* x    = (const float*)d_in[0];
    const int*   src1 = (const int*)  d_in[1];
    const int*   dst1 = (const int*)  d_in[2];
    const int*   src2 = (const int*)  d_in[3];
    const int*   dst2 = (const int*)  d_in[4];
    const float* Wl1  = (const float*)d_in[5];
    const float* Wr1  = (const float*)d_in[6];
    const float* b1   = (const float*)d_in[7];
    const float* Wl2  = (const float*)d_in[8];
    const float* Wr2  = (const float*)d_in[9];
    const float* b2   = (const float*)d_in[10];
    float* out = (float*)d_out;

    // ---- workspace layout (bf16 elems unless noted), ~69.5 MB total:
    //  xb   [N0*128]  51.2MB — bf16 x; rows >= N1 portion also hosts hb rows
    //  agg1 [N1*128]  12.8MB — layer-1 mean; CSR2 aliased here after gemm1
    //  agg2 [N2*256]  5.12MB — layer-2 mean; CSR1 aliased here before gather2
    //  wsw1/wsw2      0.4MB  — swizzled weights
    //  tiles          small  — scan tile sums
    unsigned short* xb   = (unsigned short*)d_ws;
    unsigned short* hb   = xb + (size_t)N1 * CIN;          // overlays xb rows>=N1
    unsigned short* agg1 = xb + (size_t)N0 * CIN;
    unsigned short* agg2 = agg1 + (size_t)N1 * CIN;
    unsigned short* wsw1 = agg2 + (size_t)N2 * HD;
    unsigned short* wsw2 = wsw1 + 2 * CIN * HD;
    int* tiles = (int*)(wsw2 + 2 * HD * HD);               // 64 ints scan scratch

    // CSR1 aliased into agg2's region (first written by gather2): 4.6MB <= 5.12MB
    int* deg1 = (int*)agg2;
    int* cur1 = deg1 + N1;
    int* off1 = cur1 + N1;
    int* eid1 = off1 + N1 + 1;
    // CSR2 aliased into agg1's region (agg1 dead after gemm1): 1.12MB <= 12.8MB
    int* deg2 = (int*)agg1;
    int* cur2 = deg2 + N2;
    int* off2 = cur2 + N2;
    int* eid2 = off2 + N2 + 1;

    const int nt1 = (N1 + 1023) / 1024;   // 49
    const int nt2 = (N2 + 1023) / 1024;   // 10

    // ---- dtype prep
    cvt_x_kernel<<<(N0 * CIN / 4 + 255) / 256, 256, 0, stream>>>(x, xb, N0 * CIN / 4);
    cvt_w_kernel<<<(2 * CIN * HD) / 256, 256, 0, stream>>>(Wl1, Wr1, wsw1, CIN);
    cvt_w_kernel<<<(2 * HD * HD) / 256, 256, 0, stream>>>(Wl2, Wr2, wsw2, HD);

    // ---- layer 1
    hipMemsetAsync(deg1, 0, (size_t)N1 * sizeof(int), stream);
    hist_kernel<<<(E1 + 255) / 256, 256, 0, stream>>>(dst1, deg1, E1);
    scan_partial<<<nt1, 256, 0, stream>>>(deg1, tiles, N1);
    scan_tiles<<<1, 64, 0, stream>>>(tiles, nt1);
    scan_final<<<nt1, 256, 0, stream>>>(deg1, tiles, off1, cur1, N1, E1);
    fill_kernel<<<(E1 + 255) / 256, 256, 0, stream>>>(src1, dst1, cur1, eid1, E1);
    gather_k128b<<<N1 / 4, 256, 0, stream>>>(xb, eid1, off1, agg1);
    mfma_gemm<CIN, CIN, true, true><<<N1 / 16, 256, 0, stream>>>(agg1, xb, wsw1, b1, hb);

    // ---- layer 2
    hipMemsetAsync(deg2, 0, (size_t)N2 * sizeof(int), stream);
    hist_kernel<<<(E2 + 255) / 256, 256, 0, stream>>>(dst2, deg2, E2);
    scan_partial<<<nt2, 256, 0, stream>>>(deg2, tiles, N2);
    scan_tiles<<<1, 64, 0, stream>>>(tiles, nt2);
    scan_final<<<nt2, 256, 0, stream>>>(deg2, tiles, off2, cur2, N2, E2);
    fill_kernel<<<(E2 + 255) / 256, 256, 0, stream>>>(src2, dst2, cur2, eid2, E2);
    gather_k256b<<<N2 / 4, 256, 0, stream>>>(hb, eid2, off2, agg2);
    mfma_gemm<HD, HD, false, false><<<N2 / 16, 256, 0, stream>>>(agg2, hb, wsw2, b2, out);
}

// Round 5
// 342.392 us; speedup vs baseline: 5.9534x; 1.4179x over previous
//
#include <hip/hip_runtime.h>

#define N0 200000
#define N1 50000
#define N2 10000
#define E1 1000000
#define E2 250000
#define CIN 128
#define HD  256

#define NB1  196      // ceil(N1/256) buckets, 256 dsts each
#define NB2  79       // ceil(N2/128) buckets, 128 dsts each
#define CAP1 8192     // >= mean 5120 + 43 sigma
#define CAP2 4096     // >= mean 3200 + 16 sigma

typedef __attribute__((ext_vector_type(8))) short short8;   // 8 bf16 = 4 VGPR
typedef __attribute__((ext_vector_type(4))) float f32x4;    // MFMA acc

__device__ __forceinline__ unsigned short f2bf(float f) {
    unsigned u = __builtin_bit_cast(unsigned, f);
    u = (u + 0x7fffu + ((u >> 16) & 1u)) >> 16;   // RNE
    return (unsigned short)u;
}
__device__ __forceinline__ float bf2f(unsigned short h) {
    unsigned u = ((unsigned)h) << 16;
    return __builtin_bit_cast(float, u);
}

// ---------------------------------------------------------------------------
// fp32 -> bf16 bulk convert
// ---------------------------------------------------------------------------
__global__ __launch_bounds__(256) void cvt_x_kernel(
    const float* __restrict__ x, unsigned short* __restrict__ xb, int n4)
{
    const int i = blockIdx.x * 256 + threadIdx.x;
    if (i >= n4) return;
    const float4 v = ((const float4*)x)[i];
    ushort4 o;
    o.x = f2bf(v.x); o.y = f2bf(v.y); o.z = f2bf(v.z); o.w = f2bf(v.w);
    ((ushort4*)xb)[i] = o;
}

// ---------------------------------------------------------------------------
// Swizzled bf16 B-operand for [Wl ; Wr]:
// Wsw[kt][nt][lane][j] = Wcat[kt*32 + (lane>>4)*8 + j][nt*16 + (lane&15)]
// ---------------------------------------------------------------------------
__global__ __launch_bounds__(256) void cvt_w_kernel(
    const float* __restrict__ Wl, const float* __restrict__ Wr,
    unsigned short* __restrict__ wsw, int K)
{
    const int tid = blockIdx.x * 256 + threadIdx.x;
    const int j  = tid & 7;
    const int L  = (tid >> 3) & 63;
    const int nt = (tid >> 9) & 15;
    const int kt = tid >> 13;
    const int k  = kt * 32 + (L >> 4) * 8 + j;
    const int n  = nt * 16 + (L & 15);
    const float v = (k < K) ? Wl[(size_t)k * HD + n] : Wr[(size_t)(k - K) * HD + n];
    wsw[tid] = f2bf(v);
}

// ---------------------------------------------------------------------------
// Pass 1: bin edges into dst-range buckets. Block stages 4096 edges:
// LDS bucket histogram -> ONE global atomic per (bucket, block) to claim a
// contiguous run -> packed (dstlow<<PACKSH | src) writes in ~run-local order.
// ---------------------------------------------------------------------------
template<int SHIFTB, int PACKSH, int CAP>
__global__ __launch_bounds__(256) void bin_kernel(
    const int* __restrict__ src, const int* __restrict__ dst,
    int* __restrict__ gcnt, unsigned* __restrict__ binned, int E)
{
    __shared__ int hcnt[256], hbase[256], hcur[256];
    const int t = threadIdx.x;
    hcnt[t] = 0;
    __syncthreads();

    unsigned pk[16];
    int      bk[16];
    const int e0 = blockIdx.x * 4096;
    #pragma unroll
    for (int j = 0; j < 16; j++) {
        const int e = e0 + j * 256 + t;
        if (e < E) {
            const int d = dst[e];
            const int s = src[e];
            const int b = d >> SHIFTB;
            pk[j] = ((unsigned)(d & ((1 << SHIFTB) - 1)) << PACKSH) | (unsigned)s;
            bk[j] = b;
            atomicAdd(&hcnt[b], 1);
        } else bk[j] = -1;
    }
    __syncthreads();

    hbase[t] = atomicAdd(&gcnt[t], hcnt[t]);   // t >= NB adds 0 to padding
    hcur[t]  = 0;
    __syncthreads();

    #pragma unroll
    for (int j = 0; j < 16; j++) {
        if (bk[j] >= 0) {
            const int idx = atomicAdd(&hcur[bk[j]], 1);
            binned[(size_t)bk[j] * CAP + hbase[bk[j]] + idx] = pk[j];
        }
    }
}

// ---------------------------------------------------------------------------
// Pass 2: per-bucket CSR finalize. One block per bucket:
// LDS hist of DPB local dsts -> LDS exclusive scan -> scatter src into LDS
// staging -> coalesced run write to eid; off[d] (absolute) and deg[d] out.
// ---------------------------------------------------------------------------
template<int PACKSH, int DPB, int CAP>
__global__ __launch_bounds__(256) void bfill_kernel(
    const unsigned* __restrict__ binned, const int* __restrict__ gcnt,
    int* __restrict__ off, int* __restrict__ deg, int* __restrict__ eid,
    int Ndst)
{
    __shared__ int lhist[DPB], lcur[DPB];
    __shared__ int ebuf[CAP];
    const int t = threadIdx.x;
    const int b = blockIdx.x;
    const int cnt = gcnt[b];
    const unsigned* bp = binned + (size_t)b * CAP;

    if (t < DPB) lhist[t] = 0;
    __syncthreads();

    for (int i = t; i < cnt; i += 256)
        atomicAdd(&lhist[bp[i] >> PACKSH], 1);
    __syncthreads();

    const int h0 = (t < DPB) ? lhist[t] : 0;
    __syncthreads();
    #pragma unroll
    for (int ofs = 1; ofs < DPB; ofs <<= 1) {
        const int u = (t >= ofs && t < DPB) ? lhist[t - ofs] : 0;
        __syncthreads();
        if (t < DPB) lhist[t] += u;
        __syncthreads();
    }

    if (t < DPB) {
        const int excl = lhist[t] - h0;
        lcur[t] = excl;
        const int d = b * DPB + t;
        if (d < Ndst) {
            off[d] = b * CAP + excl;
            deg[d] = h0;
        }
    }
    __syncthreads();

    for (int i = t; i < cnt; i += 256) {
        const unsigned p = bp[i];
        const int slot = atomicAdd(&lcur[p >> PACKSH], 1);
        ebuf[slot] = (int)(p & ((1u << PACKSH) - 1u));
    }
    __syncthreads();

    for (int i = t; i < cnt; i += 256)
        eid[(size_t)b * CAP + i] = ebuf[i];
}

// ---------------------------------------------------------------------------
// Gather-mean C=128 (bf16): one wave per dst row; two 32-lane halves on
// alternating edges, unroll x2 for MLP; fp32 acc; combine shfl_xor(32).
// ---------------------------------------------------------------------------
__global__ __launch_bounds__(256) void gather_k128b(
    const unsigned short* __restrict__ xb, const int* __restrict__ eid,
    const int* __restrict__ off, const int* __restrict__ deg,
    unsigned short* __restrict__ agg)
{
    const int w = blockIdx.x * 4 + (threadIdx.x >> 6);
    const int lane = threadIdx.x & 63;
    const int half = lane >> 5;
    const int l32  = lane & 31;
    const int base = off[w];
    const int n    = deg[w];

    float ax = 0.f, ay = 0.f, az = 0.f, aw = 0.f;
    int i = half;
    for (; i + 2 < n; i += 4) {
        const int s0 = eid[base + i];
        const int s1 = eid[base + i + 2];
        const ushort4 v0 = *(const ushort4*)(xb + (size_t)s0 * CIN + l32 * 4);
        const ushort4 v1 = *(const ushort4*)(xb + (size_t)s1 * CIN + l32 * 4);
        ax += bf2f(v0.x) + bf2f(v1.x);
        ay += bf2f(v0.y) + bf2f(v1.y);
        az += bf2f(v0.z) + bf2f(v1.z);
        aw += bf2f(v0.w) + bf2f(v1.w);
    }
    if (i < n) {
        const int s = eid[base + i];
        const ushort4 v = *(const ushort4*)(xb + (size_t)s * CIN + l32 * 4);
        ax += bf2f(v.x); ay += bf2f(v.y); az += bf2f(v.z); aw += bf2f(v.w);
    }
    ax += __shfl_xor(ax, 32);
    ay += __shfl_xor(ay, 32);
    az += __shfl_xor(az, 32);
    aw += __shfl_xor(aw, 32);

    if (half == 0) {
        const float s = 1.0f / fmaxf((float)n, 1.0f);
        ushort4 o;
        o.x = f2bf(ax * s); o.y = f2bf(ay * s);
        o.z = f2bf(az * s); o.w = f2bf(aw * s);
        *(ushort4*)(agg + (size_t)w * CIN + l32 * 4) = o;
    }
}

// ---------------------------------------------------------------------------
// Gather-mean C=256 (bf16): one wave per dst row, unroll x2.
// ---------------------------------------------------------------------------
__global__ __launch_bounds__(256) void gather_k256b(
    const unsigned short* __restrict__ hb, const int* __restrict__ eid,
    const int* __restrict__ off, const int* __restrict__ deg,
    unsigned short* __restrict__ agg)
{
    const int w = blockIdx.x * 4 + (threadIdx.x >> 6);
    const int lane = threadIdx.x & 63;
    const int base = off[w];
    const int n    = deg[w];

    float ax = 0.f, ay = 0.f, az = 0.f, aw = 0.f;
    int i = 0;
    for (; i + 1 < n; i += 2) {
        const int s0 = eid[base + i];
        const int s1 = eid[base + i + 1];
        const ushort4 v0 = *(const ushort4*)(hb + (size_t)s0 * HD + lane * 4);
        const ushort4 v1 = *(const ushort4*)(hb + (size_t)s1 * HD + lane * 4);
        ax += bf2f(v0.x) + bf2f(v1.x);
        ay += bf2f(v0.y) + bf2f(v1.y);
        az += bf2f(v0.z) + bf2f(v1.z);
        aw += bf2f(v0.w) + bf2f(v1.w);
    }
    if (i < n) {
        const int s = eid[base + i];
        const ushort4 v = *(const ushort4*)(hb + (size_t)s * HD + lane * 4);
        ax += bf2f(v.x); ay += bf2f(v.y); az += bf2f(v.z); aw += bf2f(v.w);
    }
    const float s = 1.0f / fmaxf((float)n, 1.0f);
    ushort4 o;
    o.x = f2bf(ax * s); o.y = f2bf(ay * s);
    o.z = f2bf(az * s); o.w = f2bf(aw * s);
    *(ushort4*)(agg + (size_t)w * HD + lane * 4) = o;
}

// ---------------------------------------------------------------------------
// MFMA GEMM:  out[m,:256] = act( [A1 | A2][m,:] @ Wsw + b )
// 16 rows/block, 4 waves x 4 n-tiles, LDS-free; B from pre-swizzled Wsw.
// ---------------------------------------------------------------------------
template<int K1, int K2, bool RELU, bool OUTBF>
__global__ __launch_bounds__(256) void mfma_gemm(
    const unsigned short* __restrict__ A1, const unsigned short* __restrict__ A2,
    const unsigned short* __restrict__ wsw, const float* __restrict__ bias,
    void* __restrict__ outp)
{
    constexpr int KT1 = K1 / 32;
    constexpr int KT  = (K1 + K2) / 32;

    const int t = threadIdx.x;
    const int w = t >> 6;
    const int L = t & 63;
    const int m = L & 15;
    const int q = L >> 4;
    const int row0 = blockIdx.x * 16;

    const unsigned short* a1p = A1 + (size_t)(row0 + m) * K1 + q * 8;
    const unsigned short* a2p = A2 + (size_t)(row0 + m) * K2 + q * 8;

    f32x4 acc[4] = {{0.f,0.f,0.f,0.f},{0.f,0.f,0.f,0.f},
                    {0.f,0.f,0.f,0.f},{0.f,0.f,0.f,0.f}};

    #pragma unroll
    for (int kt = 0; kt < KT; kt++) {
        short8 af;
        if (kt < KT1) af = *(const short8*)(a1p + kt * 32);
        else          af = *(const short8*)(a2p + (kt - KT1) * 32);
        #pragma unroll
        for (int tt = 0; tt < 4; tt++) {
            const short8 bf = *(const short8*)(
                wsw + (((size_t)kt * 16 + (w * 4 + tt)) * 64 + L) * 8);
            acc[tt] = __builtin_amdgcn_mfma_f32_16x16x32_bf16(af, bf, acc[tt], 0, 0, 0);
        }
    }

    const int orow = row0 + q * 4;
    #pragma unroll
    for (int tt = 0; tt < 4; tt++) {
        const int col = (w * 4 + tt) * 16 + m;
        const float bv = bias[col];
        #pragma unroll
        for (int r = 0; r < 4; r++) {
            float v = acc[tt][r] + bv;
            if (RELU) v = fmaxf(v, 0.0f);
            const size_t idx = (size_t)(orow + r) * HD + col;
            if (OUTBF) ((unsigned short*)outp)[idx] = f2bf(v);
            else       ((float*)outp)[idx] = v;
        }
    }
}

extern "C" void kernel_launch(void* const* d_in, const int* in_sizes, int n_in,
                              void* d_out, int out_size, void* d_ws, size_t ws_size,
                              hipStream_t stream)
{
    const float* x    = (const float*)d_in[0];
    const int*   src1 = (const int*)  d_in[1];
    const int*   dst1 = (const int*)  d_in[2];
    const int*   src2 = (const int*)  d_in[3];
    const int*   dst2 = (const int*)  d_in[4];
    const float* Wl1  = (const float*)d_in[5];
    const float* Wr1  = (const float*)d_in[6];
    const float* b1   = (const float*)d_in[7];
    const float* Wl2  = (const float*)d_in[8];
    const float* Wr2  = (const float*)d_in[9];
    const float* b2   = (const float*)d_in[10];
    float* out = (float*)d_out;

    // ---- workspace (~83 MB):
    //  xb [N0*128] bf16 (hb overlays xb rows >= N1 — xb tail dead after gather1)
    //  agg1, agg2, wsw1, wsw2 bf16
    //  gcnt[512] | off1,deg1 [N1] | off2,deg2 [N2]
    //  binned1 [NB1*CAP1] u32 (binned2 aliases; dead after bfill1)
    //  eid1    [NB1*CAP1] int (eid2 aliases; dead after gather1)
    unsigned short* xb   = (unsigned short*)d_ws;
    unsigned short* hb   = xb + (size_t)N1 * CIN;
    unsigned short* agg1 = xb + (size_t)N0 * CIN;
    unsigned short* agg2 = agg1 + (size_t)N1 * CIN;
    unsigned short* wsw1 = agg2 + (size_t)N2 * HD;
    unsigned short* wsw2 = wsw1 + 2 * CIN * HD;
    int* gcnt = (int*)(wsw2 + 2 * HD * HD);        // 512 ints (256 per layer)
    int* off1 = gcnt + 512;
    int* deg1 = off1 + N1;
    int* off2 = deg1 + N1;
    int* deg2 = off2 + N2;
    unsigned* binned1 = (unsigned*)(deg2 + N2);
    int*      eid1    = (int*)(binned1 + (size_t)NB1 * CAP1);
    unsigned* binned2 = binned1;                   // alias, disjoint lifetime
    int*      eid2    = eid1;                      // alias, disjoint lifetime
    int* gcnt2 = gcnt + 256;

    // ---- prep
    hipMemsetAsync(gcnt, 0, 512 * sizeof(int), stream);
    cvt_x_kernel<<<(N0 * CIN / 4 + 255) / 256, 256, 0, stream>>>(x, xb, N0 * CIN / 4);
    cvt_w_kernel<<<(2 * CIN * HD) / 256, 256, 0, stream>>>(Wl1, Wr1, wsw1, CIN);
    cvt_w_kernel<<<(2 * HD * HD) / 256, 256, 0, stream>>>(Wl2, Wr2, wsw2, HD);

    // ---- layer 1  (256 dsts/bucket, shift 8; pack src:18 bits)
    bin_kernel<8, 18, CAP1><<<(E1 + 4095) / 4096, 256, 0, stream>>>(
        src1, dst1, gcnt, binned1, E1);
    bfill_kernel<18, 256, CAP1><<<NB1, 256, 0, stream>>>(
        binned1, gcnt, off1, deg1, eid1, N1);
    gather_k128b<<<N1 / 4, 256, 0, stream>>>(xb, eid1, off1, deg1, agg1);
    mfma_gemm<CIN, CIN, true, true><<<N1 / 16, 256, 0, stream>>>(
        agg1, xb, wsw1, b1, hb);

    // ---- layer 2  (128 dsts/bucket, shift 7; pack src:16 bits)
    bin_kernel<7, 16, CAP2><<<(E2 + 4095) / 4096, 256, 0, stream>>>(
        src2, dst2, gcnt2, binned2, E2);
    bfill_kernel<16, 128, CAP2><<<NB2, 256, 0, stream>>>(
        binned2, gcnt2, off2, deg2, eid2, N2);
    gather_k256b<<<N2 / 4, 256, 0, stream>>>(hb, eid2, off2, deg2, agg2);
    mfma_gemm<HD, HD, false, false><<<N2 / 16, 256, 0, stream>>>(
        agg2, hb, wsw2, b2, out);
}

// Round 6
// 339.954 us; speedup vs baseline: 5.9961x; 1.0072x over previous
//
#include <hip/hip_runtime.h>

#define N0 200000
#define N1 50000
#define N2 10000
#define E1 1000000
#define E2 250000
#define CIN 128
#define HD  256

#define NB1  196      // ceil(N1/256) buckets, 256 dsts each
#define NB2  79       // ceil(N2/128) buckets, 128 dsts each
#define CAP1 8192     // >= mean 5120 + 43 sigma
#define CAP2 4096     // >= mean 3200 + 16 sigma

typedef __attribute__((ext_vector_type(8))) short short8;   // 8 bf16 = 4 VGPR
typedef __attribute__((ext_vector_type(4))) float f32x4;    // MFMA acc

__device__ __forceinline__ unsigned short f2bf(float f) {
    unsigned u = __builtin_bit_cast(unsigned, f);
    u = (u + 0x7fffu + ((u >> 16) & 1u)) >> 16;   // RNE
    return (unsigned short)u;
}
__device__ __forceinline__ float bf2f(unsigned short h) {
    unsigned u = ((unsigned)h) << 16;
    return __builtin_bit_cast(float, u);
}

// ---------------------------------------------------------------------------
// fp32 -> bf16 bulk convert
// ---------------------------------------------------------------------------
__global__ __launch_bounds__(256) void cvt_x_kernel(
    const float* __restrict__ x, unsigned short* __restrict__ xb, int n4)
{
    const int i = blockIdx.x * 256 + threadIdx.x;
    if (i >= n4) return;
    const float4 v = ((const float4*)x)[i];
    ushort4 o;
    o.x = f2bf(v.x); o.y = f2bf(v.y); o.z = f2bf(v.z); o.w = f2bf(v.w);
    ((ushort4*)xb)[i] = o;
}

// ---------------------------------------------------------------------------
// Fused prep: swizzle both weight sets to bf16 fragment order + zero gcnt.
// Wsw[kt][nt][lane][j] = Wcat[kt*32 + (lane>>4)*8 + j][nt*16 + (lane&15)]
// Blocks [0,256) -> wsw1 (K=128), [256,768) -> wsw2 (K=256). Block 0 also
// zeroes the 512-int gcnt array (prep precedes bin on the stream).
// ---------------------------------------------------------------------------
__global__ __launch_bounds__(256) void prep_kernel(
    const float* __restrict__ Wl1, const float* __restrict__ Wr1,
    const float* __restrict__ Wl2, const float* __restrict__ Wr2,
    unsigned short* __restrict__ wsw1, unsigned short* __restrict__ wsw2,
    int* __restrict__ gcnt)
{
    const int b = blockIdx.x;
    const int t = threadIdx.x;
    if (b == 0) { gcnt[t] = 0; gcnt[256 + t] = 0; }

    const float* Wl; const float* Wr; unsigned short* wsw; int K, tid;
    if (b < 256) { Wl = Wl1; Wr = Wr1; wsw = wsw1; K = CIN; tid = b * 256 + t; }
    else         { Wl = Wl2; Wr = Wr2; wsw = wsw2; K = HD;  tid = (b - 256) * 256 + t; }

    const int j  = tid & 7;
    const int L  = (tid >> 3) & 63;
    const int nt = (tid >> 9) & 15;
    const int kt = tid >> 13;
    const int k  = kt * 32 + (L >> 4) * 8 + j;
    const int n  = nt * 16 + (L & 15);
    const float v = (k < K) ? Wl[(size_t)k * HD + n] : Wr[(size_t)(k - K) * HD + n];
    wsw[tid] = f2bf(v);
}

// ---------------------------------------------------------------------------
// Pass 1: bin edges into dst-range buckets (one global atomic per
// bucket-block pair; packed (dstlow<<PACKSH | src) payloads).
// ---------------------------------------------------------------------------
template<int SHIFTB, int PACKSH, int CAP>
__global__ __launch_bounds__(256) void bin_kernel(
    const int* __restrict__ src, const int* __restrict__ dst,
    int* __restrict__ gcnt, unsigned* __restrict__ binned, int E)
{
    __shared__ int hcnt[256], hbase[256], hcur[256];
    const int t = threadIdx.x;
    hcnt[t] = 0;
    __syncthreads();

    unsigned pk[16];
    int      bk[16];
    const int e0 = blockIdx.x * 4096;
    #pragma unroll
    for (int j = 0; j < 16; j++) {
        const int e = e0 + j * 256 + t;
        if (e < E) {
            const int d = dst[e];
            const int s = src[e];
            const int b = d >> SHIFTB;
            pk[j] = ((unsigned)(d & ((1 << SHIFTB) - 1)) << PACKSH) | (unsigned)s;
            bk[j] = b;
            atomicAdd(&hcnt[b], 1);
        } else bk[j] = -1;
    }
    __syncthreads();

    hbase[t] = atomicAdd(&gcnt[t], hcnt[t]);
    hcur[t]  = 0;
    __syncthreads();

    #pragma unroll
    for (int j = 0; j < 16; j++) {
        if (bk[j] >= 0) {
            const int idx = atomicAdd(&hcur[bk[j]], 1);
            binned[(size_t)bk[j] * CAP + hbase[bk[j]] + idx] = pk[j];
        }
    }
}

// ---------------------------------------------------------------------------
// Pass 2: per-bucket CSR finalize (LDS hist -> scan -> LDS scatter ->
// coalesced eid write; off/deg out).
// ---------------------------------------------------------------------------
template<int PACKSH, int DPB, int CAP>
__global__ __launch_bounds__(256) void bfill_kernel(
    const unsigned* __restrict__ binned, const int* __restrict__ gcnt,
    int* __restrict__ off, int* __restrict__ deg, int* __restrict__ eid,
    int Ndst)
{
    __shared__ int lhist[DPB], lcur[DPB];
    __shared__ int ebuf[CAP];
    const int t = threadIdx.x;
    const int b = blockIdx.x;
    const int cnt = gcnt[b];
    const unsigned* bp = binned + (size_t)b * CAP;

    if (t < DPB) lhist[t] = 0;
    __syncthreads();

    for (int i = t; i < cnt; i += 256)
        atomicAdd(&lhist[bp[i] >> PACKSH], 1);
    __syncthreads();

    const int h0 = (t < DPB) ? lhist[t] : 0;
    __syncthreads();
    #pragma unroll
    for (int ofs = 1; ofs < DPB; ofs <<= 1) {
        const int u = (t >= ofs && t < DPB) ? lhist[t - ofs] : 0;
        __syncthreads();
        if (t < DPB) lhist[t] += u;
        __syncthreads();
    }

    if (t < DPB) {
        const int excl = lhist[t] - h0;
        lcur[t] = excl;
        const int d = b * DPB + t;
        if (d < Ndst) {
            off[d] = b * CAP + excl;
            deg[d] = h0;
        }
    }
    __syncthreads();

    for (int i = t; i < cnt; i += 256) {
        const unsigned p = bp[i];
        const int slot = atomicAdd(&lcur[p >> PACKSH], 1);
        ebuf[slot] = (int)(p & ((1u << PACKSH) - 1u));
    }
    __syncthreads();

    for (int i = t; i < cnt; i += 256)
        eid[(size_t)b * CAP + i] = ebuf[i];
}

// ---------------------------------------------------------------------------
// Gather-mean C=128 (bf16): one wave per dst row; 32-lane halves on
// alternating edges; unroll x4 (4 row loads in flight per half).
// ---------------------------------------------------------------------------
__global__ __launch_bounds__(256) void gather_k128b(
    const unsigned short* __restrict__ xb, const int* __restrict__ eid,
    const int* __restrict__ off, const int* __restrict__ deg,
    unsigned short* __restrict__ agg)
{
    const int w = blockIdx.x * 4 + (threadIdx.x >> 6);
    const int lane = threadIdx.x & 63;
    const int half = lane >> 5;
    const int l32  = lane & 31;
    const int base = off[w];
    const int n    = deg[w];

    float ax = 0.f, ay = 0.f, az = 0.f, aw = 0.f;
    int i = half;
    for (; i + 6 < n; i += 8) {
        const int s0 = eid[base + i];
        const int s1 = eid[base + i + 2];
        const int s2 = eid[base + i + 4];
        const int s3 = eid[base + i + 6];
        const ushort4 v0 = *(const ushort4*)(xb + (size_t)s0 * CIN + l32 * 4);
        const ushort4 v1 = *(const ushort4*)(xb + (size_t)s1 * CIN + l32 * 4);
        const ushort4 v2 = *(const ushort4*)(xb + (size_t)s2 * CIN + l32 * 4);
        const ushort4 v3 = *(const ushort4*)(xb + (size_t)s3 * CIN + l32 * 4);
        ax += bf2f(v0.x) + bf2f(v1.x) + bf2f(v2.x) + bf2f(v3.x);
        ay += bf2f(v0.y) + bf2f(v1.y) + bf2f(v2.y) + bf2f(v3.y);
        az += bf2f(v0.z) + bf2f(v1.z) + bf2f(v2.z) + bf2f(v3.z);
        aw += bf2f(v0.w) + bf2f(v1.w) + bf2f(v2.w) + bf2f(v3.w);
    }
    for (; i < n; i += 2) {
        const int s = eid[base + i];
        const ushort4 v = *(const ushort4*)(xb + (size_t)s * CIN + l32 * 4);
        ax += bf2f(v.x); ay += bf2f(v.y); az += bf2f(v.z); aw += bf2f(v.w);
    }
    ax += __shfl_xor(ax, 32);
    ay += __shfl_xor(ay, 32);
    az += __shfl_xor(az, 32);
    aw += __shfl_xor(aw, 32);

    if (half == 0) {
        const float s = 1.0f / fmaxf((float)n, 1.0f);
        ushort4 o;
        o.x = f2bf(ax * s); o.y = f2bf(ay * s);
        o.z = f2bf(az * s); o.w = f2bf(aw * s);
        *(ushort4*)(agg + (size_t)w * CIN + l32 * 4) = o;
    }
}

// ---------------------------------------------------------------------------
// Gather-mean C=256 (bf16): one wave per dst row, unroll x4.
// ---------------------------------------------------------------------------
__global__ __launch_bounds__(256) void gather_k256b(
    const unsigned short* __restrict__ hb, const int* __restrict__ eid,
    const int* __restrict__ off, const int* __restrict__ deg,
    unsigned short* __restrict__ agg)
{
    const int w = blockIdx.x * 4 + (threadIdx.x >> 6);
    const int lane = threadIdx.x & 63;
    const int base = off[w];
    const int n    = deg[w];

    float ax = 0.f, ay = 0.f, az = 0.f, aw = 0.f;
    int i = 0;
    for (; i + 3 < n; i += 4) {
        const int s0 = eid[base + i];
        const int s1 = eid[base + i + 1];
        const int s2 = eid[base + i + 2];
        const int s3 = eid[base + i + 3];
        const ushort4 v0 = *(const ushort4*)(hb + (size_t)s0 * HD + lane * 4);
        const ushort4 v1 = *(const ushort4*)(hb + (size_t)s1 * HD + lane * 4);
        const ushort4 v2 = *(const ushort4*)(hb + (size_t)s2 * HD + lane * 4);
        const ushort4 v3 = *(const ushort4*)(hb + (size_t)s3 * HD + lane * 4);
        ax += bf2f(v0.x) + bf2f(v1.x) + bf2f(v2.x) + bf2f(v3.x);
        ay += bf2f(v0.y) + bf2f(v1.y) + bf2f(v2.y) + bf2f(v3.y);
        az += bf2f(v0.z) + bf2f(v1.z) + bf2f(v2.z) + bf2f(v3.z);
        aw += bf2f(v0.w) + bf2f(v1.w) + bf2f(v2.w) + bf2f(v3.w);
    }
    for (; i < n; i++) {
        const int s = eid[base + i];
        const ushort4 v = *(const ushort4*)(hb + (size_t)s * HD + lane * 4);
        ax += bf2f(v.x); ay += bf2f(v.y); az += bf2f(v.z); aw += bf2f(v.w);
    }
    const float s = 1.0f / fmaxf((float)n, 1.0f);
    ushort4 o;
    o.x = f2bf(ax * s); o.y = f2bf(ay * s);
    o.z = f2bf(az * s); o.w = f2bf(aw * s);
    *(ushort4*)(agg + (size_t)w * HD + lane * 4) = o;
}

// ---------------------------------------------------------------------------
// MFMA GEMM, 64-row blocks: out[m,:256] = act( [A1|A2][m,:] @ Wsw + b ).
// 4 waves; wave w owns n-tiles 4w..4w+3 for ALL 64 rows (4 row-groups).
// B-frags (4 x short8) loaded once per kt, reused across 4 row-groups ->
// W traffic amortized 4x vs 16-row blocks. No LDS, no barriers.
// A-row clamped to M-1 for tail blocks; stores guarded.
// ---------------------------------------------------------------------------
template<int K1, int K2, bool RELU, bool OUTBF>
__global__ __launch_bounds__(256) void mfma_gemm(
    const unsigned short* __restrict__ A1, const unsigned short* __restrict__ A2,
    const unsigned short* __restrict__ wsw, const float* __restrict__ bias,
    void* __restrict__ outp, int M)
{
    constexpr int KT1 = K1 / 32;
    constexpr int KT  = (K1 + K2) / 32;

    const int t = threadIdx.x;
    const int w = t >> 6;
    const int L = t & 63;
    const int m = L & 15;
    const int q = L >> 4;
    const int row0 = blockIdx.x * 64;

    const unsigned short* a1p[4];
    const unsigned short* a2p[4];
    #pragma unroll
    for (int rg = 0; rg < 4; rg++) {
        const int r = min(row0 + rg * 16 + m, M - 1);
        a1p[rg] = A1 + (size_t)r * K1 + q * 8;
        a2p[rg] = A2 + (size_t)r * K2 + q * 8;
    }

    f32x4 acc[4][4];   // [row-group][n-tile]
    #pragma unroll
    for (int rg = 0; rg < 4; rg++)
        #pragma unroll
        for (int tt = 0; tt < 4; tt++)
            acc[rg][tt] = (f32x4){0.f, 0.f, 0.f, 0.f};

    #pragma unroll
    for (int kt = 0; kt < KT; kt++) {
        short8 bfr[4];
        #pragma unroll
        for (int tt = 0; tt < 4; tt++)
            bfr[tt] = *(const short8*)(
                wsw + (((size_t)kt * 16 + (w * 4 + tt)) * 64 + L) * 8);
        #pragma unroll
        for (int rg = 0; rg < 4; rg++) {
            short8 af;
            if (kt < KT1) af = *(const short8*)(a1p[rg] + kt * 32);
            else          af = *(const short8*)(a2p[rg] + (kt - KT1) * 32);
            #pragma unroll
            for (int tt = 0; tt < 4; tt++)
                acc[rg][tt] = __builtin_amdgcn_mfma_f32_16x16x32_bf16(
                    af, bfr[tt], acc[rg][tt], 0, 0, 0);
        }
    }

    #pragma unroll
    for (int rg = 0; rg < 4; rg++) {
        const int orow0 = row0 + rg * 16 + q * 4;
        #pragma unroll
        for (int tt = 0; tt < 4; tt++) {
            const int col = (w * 4 + tt) * 16 + m;
            const float bv = bias[col];
            #pragma unroll
            for (int r = 0; r < 4; r++) {
                const int row = orow0 + r;
                if (row < M) {
                    float v = acc[rg][tt][r] + bv;
                    if (RELU) v = fmaxf(v, 0.0f);
                    const size_t idx = (size_t)row * HD + col;
                    if (OUTBF) ((unsigned short*)outp)[idx] = f2bf(v);
                    else       ((float*)outp)[idx] = v;
                }
            }
        }
    }
}

extern "C" void kernel_launch(void* const* d_in, const int* in_sizes, int n_in,
                              void* d_out, int out_size, void* d_ws, size_t ws_size,
                              hipStream_t stream)
{
    const float* x    = (const float*)d_in[0];
    const int*   src1 = (const int*)  d_in[1];
    const int*   dst1 = (const int*)  d_in[2];
    const int*   src2 = (const int*)  d_in[3];
    const int*   dst2 = (const int*)  d_in[4];
    const float* Wl1  = (const float*)d_in[5];
    const float* Wr1  = (const float*)d_in[6];
    const float* b1   = (const float*)d_in[7];
    const float* Wl2  = (const float*)d_in[8];
    const float* Wr2  = (const float*)d_in[9];
    const float* b2   = (const float*)d_in[10];
    float* out = (float*)d_out;

    // ---- workspace (~83 MB; ws is ~400 MB so plenty of headroom):
    unsigned short* xb   = (unsigned short*)d_ws;
    unsigned short* hb   = xb + (size_t)N1 * CIN;   // overlays xb rows >= N1
    unsigned short* agg1 = xb + (size_t)N0 * CIN;
    unsigned short* agg2 = agg1 + (size_t)N1 * CIN;
    unsigned short* wsw1 = agg2 + (size_t)N2 * HD;
    unsigned short* wsw2 = wsw1 + 2 * CIN * HD;
    int* gcnt = (int*)(wsw2 + 2 * HD * HD);         // 512 ints
    int* off1 = gcnt + 512;
    int* deg1 = off1 + N1;
    int* off2 = deg1 + N1;
    int* deg2 = off2 + N2;
    unsigned* binned1 = (unsigned*)(deg2 + N2);
    int*      eid1    = (int*)(binned1 + (size_t)NB1 * CAP1);
    unsigned* binned2 = binned1;                    // alias, disjoint lifetime
    int*      eid2    = eid1;                       // alias, disjoint lifetime
    int* gcnt2 = gcnt + 256;

    // ---- prep (weight swizzle + gcnt zero) and x conversion
    prep_kernel<<<768, 256, 0, stream>>>(Wl1, Wr1, Wl2, Wr2, wsw1, wsw2, gcnt);
    cvt_x_kernel<<<(N0 * CIN / 4 + 255) / 256, 256, 0, stream>>>(x, xb, N0 * CIN / 4);

    // ---- layer 1  (256 dsts/bucket, shift 8; pack src:18 bits)
    bin_kernel<8, 18, CAP1><<<(E1 + 4095) / 4096, 256, 0, stream>>>(
        src1, dst1, gcnt, binned1, E1);
    bfill_kernel<18, 256, CAP1><<<NB1, 256, 0, stream>>>(
        binned1, gcnt, off1, deg1, eid1, N1);
    gather_k128b<<<N1 / 4, 256, 0, stream>>>(xb, eid1, off1, deg1, agg1);
    mfma_gemm<CIN, CIN, true, true><<<(N1 + 63) / 64, 256, 0, stream>>>(
        agg1, xb, wsw1, b1, hb, N1);

    // ---- layer 2  (128 dsts/bucket, shift 7; pack src:16 bits)
    bin_kernel<7, 16, CAP2><<<(E2 + 4095) / 4096, 256, 0, stream>>>(
        src2, dst2, gcnt2, binned2, E2);
    bfill_kernel<16, 128, CAP2><<<NB2, 256, 0, stream>>>(
        binned2, gcnt2, off2, deg2, eid2, N2);
    gather_k256b<<<N2 / 4, 256, 0, stream>>>(hb, eid2, off2, deg2, agg2);
    mfma_gemm<HD, HD, false, false><<<(N2 + 63) / 64, 256, 0, stream>>>(
        agg2, hb, wsw2, b2, out, N2);
}

// Round 7
// 314.083 us; speedup vs baseline: 6.4900x; 1.0824x over previous
//
#include <hip/hip_runtime.h>

#define N0 200000
#define N1 50000
#define N2 10000
#define E1 1000000
#define E2 250000
#define CIN 128
#define HD  256

#define NB1  196      // ceil(N1/256) buckets, 256 dsts each
#define NB2  79       // ceil(N2/128) buckets, 128 dsts each
#define CAP1 8192
#define CAP2 4096

#define NBIN1 489     // ceil(E1/2048)
#define NBIN2 123     // ceil(E2/2048)
#define NPREP 768
#define NCVT  25000   // N0*CIN/4 threads / 256

typedef __attribute__((ext_vector_type(8))) short short8;
typedef __attribute__((ext_vector_type(4))) float f32x4;

__device__ __forceinline__ unsigned short f2bf(float f) {
    unsigned u = __builtin_bit_cast(unsigned, f);
    u = (u + 0x7fffu + ((u >> 16) & 1u)) >> 16;   // RNE
    return (unsigned short)u;
}
__device__ __forceinline__ float bf2f(unsigned short h) {
    unsigned u = ((unsigned)h) << 16;
    return __builtin_bit_cast(float, u);
}

// ---------------------------------------------------------------------------
// bin body: 2048 edges/block -> LDS bucket hist -> 1 global atomic per
// (bucket,block) -> packed (dstlow<<PACKSH | src) scatter into bucket runs.
// ---------------------------------------------------------------------------
template<int SHIFTB, int PACKSH, int CAP>
__device__ __forceinline__ void bin_body(
    int bb, const int* __restrict__ src, const int* __restrict__ dst,
    int* __restrict__ gcnt, unsigned* __restrict__ binned, int E, int* sh)
{
    int* hcnt  = sh;
    int* hbase = sh + 256;
    int* hcur  = sh + 512;
    const int t = threadIdx.x;
    hcnt[t] = 0;
    __syncthreads();

    unsigned pk[8];
    int      bk[8];
    const int e0 = bb * 2048;
    #pragma unroll
    for (int j = 0; j < 8; j++) {
        const int e = e0 + j * 256 + t;
        if (e < E) {
            const int d = dst[e];
            const int s = src[e];
            bk[j] = d >> SHIFTB;
            pk[j] = ((unsigned)(d & ((1 << SHIFTB) - 1)) << PACKSH) | (unsigned)s;
            atomicAdd(&hcnt[bk[j]], 1);
        } else bk[j] = -1;
    }
    __syncthreads();

    hbase[t] = atomicAdd(&gcnt[t], hcnt[t]);
    hcur[t]  = 0;
    __syncthreads();

    #pragma unroll
    for (int j = 0; j < 8; j++) {
        if (bk[j] >= 0) {
            const int idx = atomicAdd(&hcur[bk[j]], 1);
            binned[(size_t)bk[j] * CAP + hbase[bk[j]] + idx] = pk[j];
        }
    }
}

// ---------------------------------------------------------------------------
// Mega-kernel A: bin1 | bin2 | weight-swizzle | x->bf16 convert.
// All four are mutually independent; bins dispatched first (blockIdx order)
// so their latency overlaps the 25000-block cvt stream.
// ---------------------------------------------------------------------------
__global__ __launch_bounds__(256) void megaA_kernel(
    const float* __restrict__ x, unsigned short* __restrict__ xb,
    const float* __restrict__ Wl1, const float* __restrict__ Wr1,
    const float* __restrict__ Wl2, const float* __restrict__ Wr2,
    unsigned short* __restrict__ wsw1, unsigned short* __restrict__ wsw2,
    const int* __restrict__ src1, const int* __restrict__ dst1,
    const int* __restrict__ src2, const int* __restrict__ dst2,
    int* __restrict__ gcnt1, int* __restrict__ gcnt2,
    unsigned* __restrict__ binned1, unsigned* __restrict__ binned2)
{
    __shared__ int sh[768];
    const int b = blockIdx.x;
    const int t = threadIdx.x;

    if (b < NBIN1) {
        bin_body<8, 18, CAP1>(b, src1, dst1, gcnt1, binned1, E1, sh);
    } else if (b < NBIN1 + NBIN2) {
        bin_body<7, 16, CAP2>(b - NBIN1, src2, dst2, gcnt2, binned2, E2, sh);
    } else if (b < NBIN1 + NBIN2 + NPREP) {
        const int pb = b - NBIN1 - NBIN2;
        const float* Wl; const float* Wr; unsigned short* wsw; int K, tid;
        if (pb < 256) { Wl = Wl1; Wr = Wr1; wsw = wsw1; K = CIN; tid = pb * 256 + t; }
        else          { Wl = Wl2; Wr = Wr2; wsw = wsw2; K = HD;  tid = (pb - 256) * 256 + t; }
        const int j  = tid & 7;
        const int L  = (tid >> 3) & 63;
        const int nt = (tid >> 9) & 15;
        const int kt = tid >> 13;
        const int k  = kt * 32 + (L >> 4) * 8 + j;
        const int n  = nt * 16 + (L & 15);
        const float v = (k < K) ? Wl[(size_t)k * HD + n]
                                : Wr[(size_t)(k - K) * HD + n];
        wsw[tid] = f2bf(v);
    } else {
        const int i = (b - NBIN1 - NBIN2 - NPREP) * 256 + t;   // < N0*CIN/4
        const float4 v = ((const float4*)x)[i];
        ushort4 o;
        o.x = f2bf(v.x); o.y = f2bf(v.y); o.z = f2bf(v.z); o.w = f2bf(v.w);
        ((ushort4*)xb)[i] = o;
    }
}

// ---------------------------------------------------------------------------
// bfill body: per-bucket CSR finalize (LDS hist -> scan -> LDS scatter ->
// coalesced eid write; off/deg out).
// ---------------------------------------------------------------------------
template<int PACKSH, int DPB, int CAP>
__device__ __forceinline__ void bfill_body(
    int b, const unsigned* __restrict__ binned, const int* __restrict__ gcnt,
    int* __restrict__ off, int* __restrict__ deg, int* __restrict__ eid,
    int Ndst, int* lhist, int* lcur, int* ebuf)
{
    const int t = threadIdx.x;
    const int cnt = gcnt[b];
    const unsigned* bp = binned + (size_t)b * CAP;

    if (t < DPB) lhist[t] = 0;
    __syncthreads();

    for (int i = t; i < cnt; i += 256)
        atomicAdd(&lhist[bp[i] >> PACKSH], 1);
    __syncthreads();

    const int h0 = (t < DPB) ? lhist[t] : 0;
    __syncthreads();
    #pragma unroll
    for (int ofs = 1; ofs < DPB; ofs <<= 1) {
        const int u = (t >= ofs && t < DPB) ? lhist[t - ofs] : 0;
        __syncthreads();
        if (t < DPB) lhist[t] += u;
        __syncthreads();
    }

    if (t < DPB) {
        const int excl = lhist[t] - h0;
        lcur[t] = excl;
        const int d = b * DPB + t;
        if (d < Ndst) {
            off[d] = b * CAP + excl;
            deg[d] = h0;
        }
    }
    __syncthreads();

    for (int i = t; i < cnt; i += 256) {
        const unsigned p = bp[i];
        const int slot = atomicAdd(&lcur[p >> PACKSH], 1);
        ebuf[slot] = (int)(p & ((1u << PACKSH) - 1u));
    }
    __syncthreads();

    for (int i = t; i < cnt; i += 256)
        eid[(size_t)b * CAP + i] = ebuf[i];
}

// Kernel B: both layers' bfill in one launch.
__global__ __launch_bounds__(256) void bfill_both(
    const unsigned* __restrict__ binned1, const int* __restrict__ gcnt1,
    int* __restrict__ off1, int* __restrict__ deg1, int* __restrict__ eid1,
    const unsigned* __restrict__ binned2, const int* __restrict__ gcnt2,
    int* __restrict__ off2, int* __restrict__ deg2, int* __restrict__ eid2)
{
    __shared__ int lhist[256], lcur[256];
    __shared__ int ebuf[CAP1];
    if (blockIdx.x < NB1)
        bfill_body<18, 256, CAP1>(blockIdx.x, binned1, gcnt1,
                                  off1, deg1, eid1, N1, lhist, lcur, ebuf);
    else
        bfill_body<16, 128, CAP2>(blockIdx.x - NB1, binned2, gcnt2,
                                  off2, deg2, eid2, N2, lhist, lcur, ebuf);
}

// ---------------------------------------------------------------------------
// Gather-mean C=128 (bf16): one wave per dst row; 32-lane halves, unroll x4.
// ---------------------------------------------------------------------------
__global__ __launch_bounds__(256) void gather_k128b(
    const unsigned short* __restrict__ xb, const int* __restrict__ eid,
    const int* __restrict__ off, const int* __restrict__ deg,
    unsigned short* __restrict__ agg)
{
    const int w = blockIdx.x * 4 + (threadIdx.x >> 6);
    const int lane = threadIdx.x & 63;
    const int half = lane >> 5;
    const int l32  = lane & 31;
    const int base = off[w];
    const int n    = deg[w];

    float ax = 0.f, ay = 0.f, az = 0.f, aw = 0.f;
    int i = half;
    for (; i + 6 < n; i += 8) {
        const int s0 = eid[base + i];
        const int s1 = eid[base + i + 2];
        const int s2 = eid[base + i + 4];
        const int s3 = eid[base + i + 6];
        const ushort4 v0 = *(const ushort4*)(xb + (size_t)s0 * CIN + l32 * 4);
        const ushort4 v1 = *(const ushort4*)(xb + (size_t)s1 * CIN + l32 * 4);
        const ushort4 v2 = *(const ushort4*)(xb + (size_t)s2 * CIN + l32 * 4);
        const ushort4 v3 = *(const ushort4*)(xb + (size_t)s3 * CIN + l32 * 4);
        ax += bf2f(v0.x) + bf2f(v1.x) + bf2f(v2.x) + bf2f(v3.x);
        ay += bf2f(v0.y) + bf2f(v1.y) + bf2f(v2.y) + bf2f(v3.y);
        az += bf2f(v0.z) + bf2f(v1.z) + bf2f(v2.z) + bf2f(v3.z);
        aw += bf2f(v0.w) + bf2f(v1.w) + bf2f(v2.w) + bf2f(v3.w);
    }
    for (; i < n; i += 2) {
        const int s = eid[base + i];
        const ushort4 v = *(const ushort4*)(xb + (size_t)s * CIN + l32 * 4);
        ax += bf2f(v.x); ay += bf2f(v.y); az += bf2f(v.z); aw += bf2f(v.w);
    }
    ax += __shfl_xor(ax, 32);
    ay += __shfl_xor(ay, 32);
    az += __shfl_xor(az, 32);
    aw += __shfl_xor(aw, 32);

    if (half == 0) {
        const float s = 1.0f / fmaxf((float)n, 1.0f);
        ushort4 o;
        o.x = f2bf(ax * s); o.y = f2bf(ay * s);
        o.z = f2bf(az * s); o.w = f2bf(aw * s);
        *(ushort4*)(agg + (size_t)w * CIN + l32 * 4) = o;
    }
}

// ---------------------------------------------------------------------------
// Gather-mean C=256 (bf16): one wave per dst row, unroll x4.
// ---------------------------------------------------------------------------
__global__ __launch_bounds__(256) void gather_k256b(
    const unsigned short* __restrict__ hb, const int* __restrict__ eid,
    const int* __restrict__ off, const int* __restrict__ deg,
    unsigned short* __restrict__ agg)
{
    const int w = blockIdx.x * 4 + (threadIdx.x >> 6);
    const int lane = threadIdx.x & 63;
    const int base = off[w];
    const int n    = deg[w];

    float ax = 0.f, ay = 0.f, az = 0.f, aw = 0.f;
    int i = 0;
    for (; i + 3 < n; i += 4) {
        const int s0 = eid[base + i];
        const int s1 = eid[base + i + 1];
        const int s2 = eid[base + i + 2];
        const int s3 = eid[base + i + 3];
        const ushort4 v0 = *(const ushort4*)(hb + (size_t)s0 * HD + lane * 4);
        const ushort4 v1 = *(const ushort4*)(hb + (size_t)s1 * HD + lane * 4);
        const ushort4 v2 = *(const ushort4*)(hb + (size_t)s2 * HD + lane * 4);
        const ushort4 v3 = *(const ushort4*)(hb + (size_t)s3 * HD + lane * 4);
        ax += bf2f(v0.x) + bf2f(v1.x) + bf2f(v2.x) + bf2f(v3.x);
        ay += bf2f(v0.y) + bf2f(v1.y) + bf2f(v2.y) + bf2f(v3.y);
        az += bf2f(v0.z) + bf2f(v1.z) + bf2f(v2.z) + bf2f(v3.z);
        aw += bf2f(v0.w) + bf2f(v1.w) + bf2f(v2.w) + bf2f(v3.w);
    }
    for (; i < n; i++) {
        const int s = eid[base + i];
        const ushort4 v = *(const ushort4*)(hb + (size_t)s * HD + lane * 4);
        ax += bf2f(v.x); ay += bf2f(v.y); az += bf2f(v.z); aw += bf2f(v.w);
    }
    const float s = 1.0f / fmaxf((float)n, 1.0f);
    ushort4 o;
    o.x = f2bf(ax * s); o.y = f2bf(ay * s);
    o.z = f2bf(az * s); o.w = f2bf(aw * s);
    *(ushort4*)(agg + (size_t)w * HD + lane * 4) = o;
}

// ---------------------------------------------------------------------------
// MFMA GEMM, 64-row blocks; B-frags held in regs across 4 row-groups.
// ---------------------------------------------------------------------------
template<int K1, int K2, bool RELU, bool OUTBF>
__global__ __launch_bounds__(256) void mfma_gemm(
    const unsigned short* __restrict__ A1, const unsigned short* __restrict__ A2,
    const unsigned short* __restrict__ wsw, const float* __restrict__ bias,
    void* __restrict__ outp, int M)
{
    constexpr int KT1 = K1 / 32;
    constexpr int KT  = (K1 + K2) / 32;

    const int t = threadIdx.x;
    const int w = t >> 6;
    const int L = t & 63;
    const int m = L & 15;
    const int q = L >> 4;
    const int row0 = blockIdx.x * 64;

    const unsigned short* a1p[4];
    const unsigned short* a2p[4];
    #pragma unroll
    for (int rg = 0; rg < 4; rg++) {
        const int r = min(row0 + rg * 16 + m, M - 1);
        a1p[rg] = A1 + (size_t)r * K1 + q * 8;
        a2p[rg] = A2 + (size_t)r * K2 + q * 8;
    }

    f32x4 acc[4][4];
    #pragma unroll
    for (int rg = 0; rg < 4; rg++)
        #pragma unroll
        for (int tt = 0; tt < 4; tt++)
            acc[rg][tt] = (f32x4){0.f, 0.f, 0.f, 0.f};

    #pragma unroll
    for (int kt = 0; kt < KT; kt++) {
        short8 bfr[4];
        #pragma unroll
        for (int tt = 0; tt < 4; tt++)
            bfr[tt] = *(const short8*)(
                wsw + (((size_t)kt * 16 + (w * 4 + tt)) * 64 + L) * 8);
        #pragma unroll
        for (int rg = 0; rg < 4; rg++) {
            short8 af;
            if (kt < KT1) af = *(const short8*)(a1p[rg] + kt * 32);
            else          af = *(const short8*)(a2p[rg] + (kt - KT1) * 32);
            #pragma unroll
            for (int tt = 0; tt < 4; tt++)
                acc[rg][tt] = __builtin_amdgcn_mfma_f32_16x16x32_bf16(
                    af, bfr[tt], acc[rg][tt], 0, 0, 0);
        }
    }

    #pragma unroll
    for (int rg = 0; rg < 4; rg++) {
        const int orow0 = row0 + rg * 16 + q * 4;
        #pragma unroll
        for (int tt = 0; tt < 4; tt++) {
            const int col = (w * 4 + tt) * 16 + m;
            const float bv = bias[col];
            #pragma unroll
            for (int r = 0; r < 4; r++) {
                const int row = orow0 + r;
                if (row < M) {
                    float v = acc[rg][tt][r] + bv;
                    if (RELU) v = fmaxf(v, 0.0f);
                    const size_t idx = (size_t)row * HD + col;
                    if (OUTBF) ((unsigned short*)outp)[idx] = f2bf(v);
                    else       ((float*)outp)[idx] = v;
                }
            }
        }
    }
}

extern "C" void kernel_launch(void* const* d_in, const int* in_sizes, int n_in,
                              void* d_out, int out_size, void* d_ws, size_t ws_size,
                              hipStream_t stream)
{
    const float* x    = (const float*)d_in[0];
    const int*   src1 = (const int*)  d_in[1];
    const int*   dst1 = (const int*)  d_in[2];
    const int*   src2 = (const int*)  d_in[3];
    const int*   dst2 = (const int*)  d_in[4];
    const float* Wl1  = (const float*)d_in[5];
    const float* Wr1  = (const float*)d_in[6];
    const float* b1   = (const float*)d_in[7];
    const float* Wl2  = (const float*)d_in[8];
    const float* Wr2  = (const float*)d_in[9];
    const float* b2   = (const float*)d_in[10];
    float* out = (float*)d_out;

    // ---- workspace (~86 MB, no aliasing between the two layers' CSR now):
    unsigned short* xb   = (unsigned short*)d_ws;
    unsigned short* hb   = xb + (size_t)N1 * CIN;   // overlays xb rows >= N1
    unsigned short* agg1 = xb + (size_t)N0 * CIN;
    unsigned short* agg2 = agg1 + (size_t)N1 * CIN;
    unsigned short* wsw1 = agg2 + (size_t)N2 * HD;
    unsigned short* wsw2 = wsw1 + 2 * CIN * HD;
    int* gcnt1 = (int*)(wsw2 + 2 * HD * HD);        // 256 ints
    int* gcnt2 = gcnt1 + 256;                       // 256 ints
    int* off1  = gcnt2 + 256;
    int* deg1  = off1 + N1;
    int* off2  = deg1 + N1;
    int* deg2  = off2 + N2;
    unsigned* binned1 = (unsigned*)(deg2 + N2);
    int*      eid1    = (int*)(binned1 + (size_t)NB1 * CAP1);
    unsigned* binned2 = (unsigned*)(eid1 + (size_t)NB1 * CAP1);
    int*      eid2    = (int*)(binned2 + (size_t)NB2 * CAP2);

    hipMemsetAsync(gcnt1, 0, 512 * sizeof(int), stream);

    // A: bin1 | bin2 | weight swizzle | x->bf16  (all independent)
    megaA_kernel<<<NBIN1 + NBIN2 + NPREP + NCVT, 256, 0, stream>>>(
        x, xb, Wl1, Wr1, Wl2, Wr2, wsw1, wsw2,
        src1, dst1, src2, dst2, gcnt1, gcnt2, binned1, binned2);

    // B: both CSR finalizes
    bfill_both<<<NB1 + NB2, 256, 0, stream>>>(
        binned1, gcnt1, off1, deg1, eid1,
        binned2, gcnt2, off2, deg2, eid2);

    // layer 1 compute
    gather_k128b<<<N1 / 4, 256, 0, stream>>>(xb, eid1, off1, deg1, agg1);
    mfma_gemm<CIN, CIN, true, true><<<(N1 + 63) / 64, 256, 0, stream>>>(
        agg1, xb, wsw1, b1, hb, N1);

    // layer 2 compute
    gather_k256b<<<N2 / 4, 256, 0, stream>>>(hb, eid2, off2, deg2, agg2);
    mfma_gemm<HD, HD, false, false><<<(N2 + 63) / 64, 256, 0, stream>>>(
        agg2, hb, wsw2, b2, out, N2);
}

// Round 8
// 310.165 us; speedup vs baseline: 6.5720x; 1.0126x over previous
//
#include <hip/hip_runtime.h>

#define N0 200000
#define N1 50000
#define N2 10000
#define E1 1000000
#define E2 250000
#define CIN 128
#define HD  256

// Layer-1 buckets: 128 dsts each
#define SH1   7
#define PK1   18        // src1 < 2^18
#define NB1   391       // ceil(N1/128)
#define CAP1  3072      // mean 2560 + 10 sigma
#define DPB1  128
// Layer-2 buckets: 64 dsts each
#define SH2   6
#define PK2   16        // src2 < 2^16
#define NB2   157       // ceil(N2/64)
#define CAP2  2048      // mean 1600 + 11 sigma
#define DPB2  64

#define NBIN1 489       // ceil(E1/2048)
#define NBIN2 123       // ceil(E2/2048)
#define NPREP 768
#define NCVT  25000     // N0*CIN/4 / 256 exactly

typedef __attribute__((ext_vector_type(8))) short short8;
typedef __attribute__((ext_vector_type(4))) float f32x4;

__device__ __forceinline__ unsigned short f2bf(float f) {
    unsigned u = __builtin_bit_cast(unsigned, f);
    u = (u + 0x7fffu + ((u >> 16) & 1u)) >> 16;   // RNE
    return (unsigned short)u;
}
__device__ __forceinline__ float bf2f(unsigned short h) {
    unsigned u = ((unsigned)h) << 16;
    return __builtin_bit_cast(float, u);
}

// ---------------------------------------------------------------------------
// bin body: 2048 edges/block -> 512-slot LDS bucket hist -> 1 global atomic
// per (bucket,block) -> packed (dstlow<<PACKSH | src) scatter to bucket runs.
// ---------------------------------------------------------------------------
template<int SHIFTB, int PACKSH, int CAP>
__device__ __forceinline__ void bin_body(
    int bb, const int* __restrict__ src, const int* __restrict__ dst,
    int* __restrict__ gcnt, unsigned* __restrict__ binned, int E, int* sh)
{
    int* hcnt  = sh;          // 512
    int* hbase = sh + 512;    // 512
    int* hcur  = sh + 1024;   // 512
    const int t = threadIdx.x;
    hcnt[t] = 0; hcnt[t + 256] = 0;
    __syncthreads();

    unsigned pk[8];
    int      bk[8];
    const int e0 = bb * 2048;
    #pragma unroll
    for (int j = 0; j < 8; j++) {
        const int e = e0 + j * 256 + t;
        if (e < E) {
            const int d = dst[e];
            const int s = src[e];
            bk[j] = d >> SHIFTB;
            pk[j] = ((unsigned)(d & ((1 << SHIFTB) - 1)) << PACKSH) | (unsigned)s;
            atomicAdd(&hcnt[bk[j]], 1);
        } else bk[j] = -1;
    }
    __syncthreads();

    hbase[t]       = atomicAdd(&gcnt[t], hcnt[t]);             hcur[t] = 0;
    hbase[t + 256] = atomicAdd(&gcnt[t + 256], hcnt[t + 256]); hcur[t + 256] = 0;
    __syncthreads();

    #pragma unroll
    for (int j = 0; j < 8; j++) {
        if (bk[j] >= 0) {
            const int idx = atomicAdd(&hcur[bk[j]], 1);
            binned[(size_t)bk[j] * CAP + hbase[bk[j]] + idx] = pk[j];
        }
    }
}

// ---------------------------------------------------------------------------
// Mega-kernel A: bin1 | bin2 | weight-swizzle | x->bf16 convert.
// ---------------------------------------------------------------------------
__global__ __launch_bounds__(256) void megaA_kernel(
    const float* __restrict__ x, unsigned short* __restrict__ xb,
    const float* __restrict__ Wl1, const float* __restrict__ Wr1,
    const float* __restrict__ Wl2, const float* __restrict__ Wr2,
    unsigned short* __restrict__ wsw1, unsigned short* __restrict__ wsw2,
    const int* __restrict__ src1, const int* __restrict__ dst1,
    const int* __restrict__ src2, const int* __restrict__ dst2,
    int* __restrict__ gcnt1, int* __restrict__ gcnt2,
    unsigned* __restrict__ binned1, unsigned* __restrict__ binned2)
{
    __shared__ int sh[1536];
    const int b = blockIdx.x;
    const int t = threadIdx.x;

    if (b < NBIN1) {
        bin_body<SH1, PK1, CAP1>(b, src1, dst1, gcnt1, binned1, E1, sh);
    } else if (b < NBIN1 + NBIN2) {
        bin_body<SH2, PK2, CAP2>(b - NBIN1, src2, dst2, gcnt2, binned2, E2, sh);
    } else if (b < NBIN1 + NBIN2 + NPREP) {
        const int pb = b - NBIN1 - NBIN2;
        const float* Wl; const float* Wr; unsigned short* wsw; int K, tid;
        if (pb < 256) { Wl = Wl1; Wr = Wr1; wsw = wsw1; K = CIN; tid = pb * 256 + t; }
        else          { Wl = Wl2; Wr = Wr2; wsw = wsw2; K = HD;  tid = (pb - 256) * 256 + t; }
        const int j  = tid & 7;
        const int L  = (tid >> 3) & 63;
        const int nt = (tid >> 9) & 15;
        const int kt = tid >> 13;
        const int k  = kt * 32 + (L >> 4) * 8 + j;
        const int n  = nt * 16 + (L & 15);
        const float v = (k < K) ? Wl[(size_t)k * HD + n]
                                : Wr[(size_t)(k - K) * HD + n];
        wsw[tid] = f2bf(v);
    } else {
        const int i = (b - NBIN1 - NBIN2 - NPREP) * 256 + t;   // exact cover
        const float4 v = ((const float4*)x)[i];
        ushort4 o;
        o.x = f2bf(v.x); o.y = f2bf(v.y); o.z = f2bf(v.z); o.w = f2bf(v.w);
        ((ushort4*)xb)[i] = o;
    }
}

// ---------------------------------------------------------------------------
// Layer-1 mega: one block per 128-dst bucket, 512 threads (8 waves).
//  A) CSR-finalize bucket in LDS (ebuf, loff/lcur)
//  B) gather-mean 128 rows from xb, write bf16 means to LDS in MFMA A-frag
//     order  aggT[kt][row][q][8]
//  C) GEMM: wave w = 16-row m-tile; A(agg) from LDS, A2(x_dst) from global,
//     B from pre-swizzled wsw1 (L2); out = relu(.. + b1) -> hb (bf16)
// ---------------------------------------------------------------------------
__global__ __launch_bounds__(512) void layer1_mega(
    const unsigned short* __restrict__ xb,
    const unsigned* __restrict__ binned1, const int* __restrict__ gcnt1,
    const unsigned short* __restrict__ wsw1, const float* __restrict__ bias,
    unsigned short* __restrict__ hb)
{
    __shared__ int ebuf[CAP1];
    __shared__ int lhist[DPB1], loff[DPB1], lcur[DPB1];
    __shared__ __align__(16) unsigned short aggT[4 * 128 * 4 * 8];  // 32 KB

    const int t = threadIdx.x;
    const int b = blockIdx.x;
    const int cnt = gcnt1[b];
    const unsigned* bp = binned1 + (size_t)b * CAP1;

    // ---- A: bucket CSR in LDS
    if (t < DPB1) lhist[t] = 0;
    __syncthreads();
    for (int i = t; i < cnt; i += 512)
        atomicAdd(&lhist[bp[i] >> PK1], 1);
    __syncthreads();
    const int h0 = (t < DPB1) ? lhist[t] : 0;
    __syncthreads();
    #pragma unroll
    for (int ofs = 1; ofs < DPB1; ofs <<= 1) {
        const int u = (t >= ofs && t < DPB1) ? lhist[t - ofs] : 0;
        __syncthreads();
        if (t < DPB1) lhist[t] += u;
        __syncthreads();
    }
    if (t < DPB1) { loff[t] = lhist[t] - h0; lcur[t] = lhist[t] - h0; }
    __syncthreads();
    for (int i = t; i < cnt; i += 512) {
        const unsigned p = bp[i];
        const int slot = atomicAdd(&lcur[p >> PK1], 1);
        ebuf[slot] = (int)(p & ((1u << PK1) - 1u));
    }
    __syncthreads();

    // ---- B: gather 128 rows (wave per row, 16 rounds)
    const int w = t >> 6, L = t & 63, half = L >> 5, l32 = L & 31;
    const int ktw = l32 >> 3, qw = (l32 >> 1) & 3, jo = (l32 & 1) * 4;
    for (int r = w; r < DPB1; r += 8) {
        const int rg = b * DPB1 + r;
        if (rg < N1) {
            const int base = loff[r];
            const int n    = lcur[r] - loff[r];
            float ax = 0.f, ay = 0.f, az = 0.f, aw = 0.f;
            int i = half;
            for (; i + 6 < n; i += 8) {
                const int s0 = ebuf[base + i];
                const int s1 = ebuf[base + i + 2];
                const int s2 = ebuf[base + i + 4];
                const int s3 = ebuf[base + i + 6];
                const ushort4 v0 = *(const ushort4*)(xb + (size_t)s0 * CIN + l32 * 4);
                const ushort4 v1 = *(const ushort4*)(xb + (size_t)s1 * CIN + l32 * 4);
                const ushort4 v2 = *(const ushort4*)(xb + (size_t)s2 * CIN + l32 * 4);
                const ushort4 v3 = *(const ushort4*)(xb + (size_t)s3 * CIN + l32 * 4);
                ax += bf2f(v0.x) + bf2f(v1.x) + bf2f(v2.x) + bf2f(v3.x);
                ay += bf2f(v0.y) + bf2f(v1.y) + bf2f(v2.y) + bf2f(v3.y);
                az += bf2f(v0.z) + bf2f(v1.z) + bf2f(v2.z) + bf2f(v3.z);
                aw += bf2f(v0.w) + bf2f(v1.w) + bf2f(v2.w) + bf2f(v3.w);
            }
            for (; i < n; i += 2) {
                const int s = ebuf[base + i];
                const ushort4 v = *(const ushort4*)(xb + (size_t)s * CIN + l32 * 4);
                ax += bf2f(v.x); ay += bf2f(v.y); az += bf2f(v.z); aw += bf2f(v.w);
            }
            ax += __shfl_xor(ax, 32);
            ay += __shfl_xor(ay, 32);
            az += __shfl_xor(az, 32);
            aw += __shfl_xor(aw, 32);
            if (half == 0) {
                const float s = 1.0f / fmaxf((float)n, 1.0f);
                ushort4 o;
                o.x = f2bf(ax * s); o.y = f2bf(ay * s);
                o.z = f2bf(az * s); o.w = f2bf(aw * s);
                *(ushort4*)&aggT[(((ktw * 128 + r) * 4 + qw) * 8) + jo] = o;
            }
        }
    }
    __syncthreads();

    // ---- C: GEMM, wave w = m-tile w (rows w*16..w*16+15 of bucket)
    const int m = L & 15, q = L >> 4;
    const int row_l = w * 16 + m;
    const int rg2 = min(b * DPB1 + row_l, N1 - 1);
    const unsigned short* a2p = xb + (size_t)rg2 * CIN + q * 8;

    f32x4 acc[16];
    #pragma unroll
    for (int nt = 0; nt < 16; nt++) acc[nt] = (f32x4){0.f, 0.f, 0.f, 0.f};

    #pragma unroll
    for (int kt = 0; kt < 8; kt++) {
        short8 af;
        if (kt < 4) af = *(const short8*)&aggT[((kt * 128 + row_l) * 4 + q) * 8];
        else        af = *(const short8*)(a2p + (kt - 4) * 32);
        #pragma unroll
        for (int nt = 0; nt < 16; nt++) {
            const short8 bf = *(const short8*)(
                wsw1 + (((size_t)kt * 16 + nt) * 64 + L) * 8);
            acc[nt] = __builtin_amdgcn_mfma_f32_16x16x32_bf16(af, bf, acc[nt], 0, 0, 0);
        }
    }

    const int orow0 = b * DPB1 + w * 16 + q * 4;
    #pragma unroll
    for (int nt = 0; nt < 16; nt++) {
        const int col = nt * 16 + m;
        const float bv = bias[col];
        #pragma unroll
        for (int r = 0; r < 4; r++) {
            const int row = orow0 + r;
            if (row < N1) {
                const float v = fmaxf(acc[nt][r] + bv, 0.0f);
                hb[(size_t)row * HD + col] = f2bf(v);
            }
        }
    }
}

// ---------------------------------------------------------------------------
// Layer-2 mega: one block per 64-dst bucket, 512 threads.
//  B) full-wave rows (64 lanes x ushort4 = 256 cols), x4 ILP
//  C) 4 m-tiles x 2 n-halves across 8 waves; fp32 out + bias, no relu.
// ---------------------------------------------------------------------------
__global__ __launch_bounds__(512) void layer2_mega(
    const unsigned short* __restrict__ hb,
    const unsigned* __restrict__ binned2, const int* __restrict__ gcnt2,
    const unsigned short* __restrict__ wsw2, const float* __restrict__ bias,
    float* __restrict__ outp)
{
    __shared__ int ebuf[CAP2];
    __shared__ int lhist[DPB2], loff[DPB2], lcur[DPB2];
    __shared__ __align__(16) unsigned short aggT[8 * 64 * 4 * 8];   // 32 KB

    const int t = threadIdx.x;
    const int b = blockIdx.x;
    const int cnt = gcnt2[b];
    const unsigned* bp = binned2 + (size_t)b * CAP2;

    if (t < DPB2) lhist[t] = 0;
    __syncthreads();
    for (int i = t; i < cnt; i += 512)
        atomicAdd(&lhist[bp[i] >> PK2], 1);
    __syncthreads();
    const int h0 = (t < DPB2) ? lhist[t] : 0;
    __syncthreads();
    #pragma unroll
    for (int ofs = 1; ofs < DPB2; ofs <<= 1) {
        const int u = (t >= ofs && t < DPB2) ? lhist[t - ofs] : 0;
        __syncthreads();
        if (t < DPB2) lhist[t] += u;
        __syncthreads();
    }
    if (t < DPB2) { loff[t] = lhist[t] - h0; lcur[t] = lhist[t] - h0; }
    __syncthreads();
    for (int i = t; i < cnt; i += 512) {
        const unsigned p = bp[i];
        const int slot = atomicAdd(&lcur[p >> PK2], 1);
        ebuf[slot] = (int)(p & ((1u << PK2) - 1u));
    }
    __syncthreads();

    const int w = t >> 6, L = t & 63;
    const int kt2 = L >> 3, q2 = (L >> 1) & 3, jo2 = (L & 1) * 4;
    for (int r = w; r < DPB2; r += 8) {
        const int rg = b * DPB2 + r;
        if (rg < N2) {
            const int base = loff[r];
            const int n    = lcur[r] - loff[r];
            float ax = 0.f, ay = 0.f, az = 0.f, aw = 0.f;
            int i = 0;
            for (; i + 3 < n; i += 4) {
                const int s0 = ebuf[base + i];
                const int s1 = ebuf[base + i + 1];
                const int s2 = ebuf[base + i + 2];
                const int s3 = ebuf[base + i + 3];
                const ushort4 v0 = *(const ushort4*)(hb + (size_t)s0 * HD + L * 4);
                const ushort4 v1 = *(const ushort4*)(hb + (size_t)s1 * HD + L * 4);
                const ushort4 v2 = *(const ushort4*)(hb + (size_t)s2 * HD + L * 4);
                const ushort4 v3 = *(const ushort4*)(hb + (size_t)s3 * HD + L * 4);
                ax += bf2f(v0.x) + bf2f(v1.x) + bf2f(v2.x) + bf2f(v3.x);
                ay += bf2f(v0.y) + bf2f(v1.y) + bf2f(v2.y) + bf2f(v3.y);
                az += bf2f(v0.z) + bf2f(v1.z) + bf2f(v2.z) + bf2f(v3.z);
                aw += bf2f(v0.w) + bf2f(v1.w) + bf2f(v2.w) + bf2f(v3.w);
            }
            for (; i < n; i++) {
                const int s = ebuf[base + i];
                const ushort4 v = *(const ushort4*)(hb + (size_t)s * HD + L * 4);
                ax += bf2f(v.x); ay += bf2f(v.y); az += bf2f(v.z); aw += bf2f(v.w);
            }
            const float s = 1.0f / fmaxf((float)n, 1.0f);
            ushort4 o;
            o.x = f2bf(ax * s); o.y = f2bf(ay * s);
            o.z = f2bf(az * s); o.w = f2bf(aw * s);
            *(ushort4*)&aggT[(((kt2 * 64 + r) * 4 + q2) * 8) + jo2] = o;
        }
    }
    __syncthreads();

    // C: wave w -> m-tile (w&3), n-half (w>>2)
    const int m = L & 15, q = L >> 4;
    const int mt = w & 3, nh = w >> 2;
    const int row_l = mt * 16 + m;
    const int rg2 = min(b * DPB2 + row_l, N2 - 1);
    const unsigned short* a2p = hb + (size_t)rg2 * HD + q * 8;

    f32x4 acc[8];
    #pragma unroll
    for (int nt = 0; nt < 8; nt++) acc[nt] = (f32x4){0.f, 0.f, 0.f, 0.f};

    #pragma unroll
    for (int kt = 0; kt < 16; kt++) {
        short8 af;
        if (kt < 8) af = *(const short8*)&aggT[((kt * 64 + row_l) * 4 + q) * 8];
        else        af = *(const short8*)(a2p + (kt - 8) * 32);
        #pragma unroll
        for (int nt = 0; nt < 8; nt++) {
            const short8 bf = *(const short8*)(
                wsw2 + (((size_t)kt * 16 + (nh * 8 + nt)) * 64 + L) * 8);
            acc[nt] = __builtin_amdgcn_mfma_f32_16x16x32_bf16(af, bf, acc[nt], 0, 0, 0);
        }
    }

    const int orow0 = b * DPB2 + mt * 16 + q * 4;
    #pragma unroll
    for (int nt = 0; nt < 8; nt++) {
        const int col = (nh * 8 + nt) * 16 + m;
        const float bv = bias[col];
        #pragma unroll
        for (int r = 0; r < 4; r++) {
            const int row = orow0 + r;
            if (row < N2)
                outp[(size_t)row * HD + col] = acc[nt][r] + bv;
        }
    }
}

extern "C" void kernel_launch(void* const* d_in, const int* in_sizes, int n_in,
                              void* d_out, int out_size, void* d_ws, size_t ws_size,
                              hipStream_t stream)
{
    const float* x    = (const float*)d_in[0];
    const int*   src1 = (const int*)  d_in[1];
    const int*   dst1 = (const int*)  d_in[2];
    const int*   src2 = (const int*)  d_in[3];
    const int*   dst2 = (const int*)  d_in[4];
    const float* Wl1  = (const float*)d_in[5];
    const float* Wr1  = (const float*)d_in[6];
    const float* b1   = (const float*)d_in[7];
    const float* Wl2  = (const float*)d_in[8];
    const float* Wr2  = (const float*)d_in[9];
    const float* b2   = (const float*)d_in[10];
    float* out = (float*)d_out;

    // ---- workspace (~83 MB): xb | hb (separate!) | wsw1 | wsw2 | gcnt | bins
    unsigned short* xb   = (unsigned short*)d_ws;
    unsigned short* hb   = xb + (size_t)N0 * CIN;
    unsigned short* wsw1 = hb + (size_t)N1 * HD;
    unsigned short* wsw2 = wsw1 + 2 * CIN * HD;
    int* gcnt1 = (int*)(wsw2 + 2 * HD * HD);        // 512
    int* gcnt2 = gcnt1 + 512;                       // 512
    unsigned* binned1 = (unsigned*)(gcnt2 + 512);   // NB1*CAP1
    unsigned* binned2 = binned1 + (size_t)NB1 * CAP1;

    hipMemsetAsync(gcnt1, 0, 1024 * sizeof(int), stream);

    megaA_kernel<<<NBIN1 + NBIN2 + NPREP + NCVT, 256, 0, stream>>>(
        x, xb, Wl1, Wr1, Wl2, Wr2, wsw1, wsw2,
        src1, dst1, src2, dst2, gcnt1, gcnt2, binned1, binned2);

    layer1_mega<<<NB1, 512, 0, stream>>>(xb, binned1, gcnt1, wsw1, b1, hb);
    layer2_mega<<<NB2, 512, 0, stream>>>(hb, binned2, gcnt2, wsw2, b2, out);
}

// Round 9
// 306.784 us; speedup vs baseline: 6.6444x; 1.0110x over previous
//
#include <hip/hip_runtime.h>

#define N0 200000
#define N1 50000
#define N2 10000
#define E1 1000000
#define E2 250000
#define CIN 128
#define HD  256

// Layer-1 buckets: 64 dsts each
#define SH1   6
#define PK1   18        // src1 < 2^18
#define NB1   782       // ceil(N1/64)
#define CAP1  2048      // mean 1279 + ~21 sigma
#define DPB1  64
// Layer-2 buckets: 16 dsts each
#define SH2   4
#define PK2   16        // src2 < 2^16
#define NB2   625       // 10000/16 exact
#define CAP2  640       // mean 400 + 12 sigma
#define DPB2  16

#define NBIN1 489       // ceil(E1/2048)
#define NBIN2 123       // ceil(E2/2048)
#define NPREP 768
#define NCVT  25000     // N0*CIN/4 / 256 exactly

typedef __attribute__((ext_vector_type(8))) short short8;
typedef __attribute__((ext_vector_type(4))) float f32x4;

__device__ __forceinline__ unsigned short f2bf(float f) {
    unsigned u = __builtin_bit_cast(unsigned, f);
    u = (u + 0x7fffu + ((u >> 16) & 1u)) >> 16;   // RNE
    return (unsigned short)u;
}
__device__ __forceinline__ float bf2f(unsigned short h) {
    unsigned u = ((unsigned)h) << 16;
    return __builtin_bit_cast(float, u);
}

// ---------------------------------------------------------------------------
// bin body: 2048 edges/block -> 1024-slot LDS bucket hist -> 1 global atomic
// per (bucket,block) -> packed (dstlow<<PACKSH | src) scatter to bucket runs.
// ---------------------------------------------------------------------------
template<int SHIFTB, int PACKSH, int CAP>
__device__ __forceinline__ void bin_body(
    int bb, const int* __restrict__ src, const int* __restrict__ dst,
    int* __restrict__ gcnt, unsigned* __restrict__ binned, int E, int* sh)
{
    int* hcnt  = sh;           // 1024
    int* hbase = sh + 1024;    // 1024
    int* hcur  = sh + 2048;    // 1024
    const int t = threadIdx.x;
    #pragma unroll
    for (int j = 0; j < 4; j++) hcnt[t + j * 256] = 0;
    __syncthreads();

    unsigned pk[8];
    int      bk[8];
    const int e0 = bb * 2048;
    #pragma unroll
    for (int j = 0; j < 8; j++) {
        const int e = e0 + j * 256 + t;
        if (e < E) {
            const int d = dst[e];
            const int s = src[e];
            bk[j] = d >> SHIFTB;
            pk[j] = ((unsigned)(d & ((1 << SHIFTB) - 1)) << PACKSH) | (unsigned)s;
            atomicAdd(&hcnt[bk[j]], 1);
        } else bk[j] = -1;
    }
    __syncthreads();

    #pragma unroll
    for (int j = 0; j < 4; j++) {
        const int i = t + j * 256;
        hbase[i] = atomicAdd(&gcnt[i], hcnt[i]);
        hcur[i]  = 0;
    }
    __syncthreads();

    #pragma unroll
    for (int j = 0; j < 8; j++) {
        if (bk[j] >= 0) {
            const int idx = atomicAdd(&hcur[bk[j]], 1);
            binned[(size_t)bk[j] * CAP + hbase[bk[j]] + idx] = pk[j];
        }
    }
}

// ---------------------------------------------------------------------------
// Mega-kernel A: bin1 | bin2 | weight-swizzle | x->bf16 convert.
// ---------------------------------------------------------------------------
__global__ __launch_bounds__(256) void megaA_kernel(
    const float* __restrict__ x, unsigned short* __restrict__ xb,
    const float* __restrict__ Wl1, const float* __restrict__ Wr1,
    const float* __restrict__ Wl2, const float* __restrict__ Wr2,
    unsigned short* __restrict__ wsw1, unsigned short* __restrict__ wsw2,
    const int* __restrict__ src1, const int* __restrict__ dst1,
    const int* __restrict__ src2, const int* __restrict__ dst2,
    int* __restrict__ gcnt1, int* __restrict__ gcnt2,
    unsigned* __restrict__ binned1, unsigned* __restrict__ binned2)
{
    __shared__ int sh[3072];
    const int b = blockIdx.x;
    const int t = threadIdx.x;

    if (b < NBIN1) {
        bin_body<SH1, PK1, CAP1>(b, src1, dst1, gcnt1, binned1, E1, sh);
    } else if (b < NBIN1 + NBIN2) {
        bin_body<SH2, PK2, CAP2>(b - NBIN1, src2, dst2, gcnt2, binned2, E2, sh);
    } else if (b < NBIN1 + NBIN2 + NPREP) {
        const int pb = b - NBIN1 - NBIN2;
        const float* Wl; const float* Wr; unsigned short* wsw; int K, tid;
        if (pb < 256) { Wl = Wl1; Wr = Wr1; wsw = wsw1; K = CIN; tid = pb * 256 + t; }
        else          { Wl = Wl2; Wr = Wr2; wsw = wsw2; K = HD;  tid = (pb - 256) * 256 + t; }
        const int j  = tid & 7;
        const int L  = (tid >> 3) & 63;
        const int nt = (tid >> 9) & 15;
        const int kt = tid >> 13;
        const int k  = kt * 32 + (L >> 4) * 8 + j;
        const int n  = nt * 16 + (L & 15);
        const float v = (k < K) ? Wl[(size_t)k * HD + n]
                                : Wr[(size_t)(k - K) * HD + n];
        wsw[tid] = f2bf(v);
    } else {
        const int i = (b - NBIN1 - NBIN2 - NPREP) * 256 + t;   // exact cover
        const float4 v = ((const float4*)x)[i];
        ushort4 o;
        o.x = f2bf(v.x); o.y = f2bf(v.y); o.z = f2bf(v.z); o.w = f2bf(v.w);
        ((ushort4*)xb)[i] = o;
    }
}

// ---------------------------------------------------------------------------
// Layer-1 mega: one block per 64-dst bucket, 512 threads (8 waves).
//  A) CSR-finalize bucket in LDS   B) gather-mean 64 rows -> LDS A-frags
//  C) 4 m-tiles x 2 n-halves GEMM -> hb = relu(.. + b1), bf16
// ---------------------------------------------------------------------------
__global__ __launch_bounds__(512) void layer1_mega(
    const unsigned short* __restrict__ xb,
    const unsigned* __restrict__ binned1, const int* __restrict__ gcnt1,
    const unsigned short* __restrict__ wsw1, const float* __restrict__ bias,
    unsigned short* __restrict__ hb)
{
    __shared__ int ebuf[CAP1];
    __shared__ int lhist[DPB1], loff[DPB1], lcur[DPB1];
    __shared__ __align__(16) unsigned short aggT[4 * DPB1 * 4 * 8];  // 16 KB

    const int t = threadIdx.x;
    const int b = blockIdx.x;
    const int cnt = gcnt1[b];
    const unsigned* bp = binned1 + (size_t)b * CAP1;

    // ---- A: bucket CSR in LDS
    if (t < DPB1) lhist[t] = 0;
    __syncthreads();
    for (int i = t; i < cnt; i += 512)
        atomicAdd(&lhist[bp[i] >> PK1], 1);
    __syncthreads();
    const int h0 = (t < DPB1) ? lhist[t] : 0;
    __syncthreads();
    #pragma unroll
    for (int ofs = 1; ofs < DPB1; ofs <<= 1) {
        const int u = (t >= ofs && t < DPB1) ? lhist[t - ofs] : 0;
        __syncthreads();
        if (t < DPB1) lhist[t] += u;
        __syncthreads();
    }
    if (t < DPB1) { loff[t] = lhist[t] - h0; lcur[t] = lhist[t] - h0; }
    __syncthreads();
    for (int i = t; i < cnt; i += 512) {
        const unsigned p = bp[i];
        const int slot = atomicAdd(&lcur[p >> PK1], 1);
        ebuf[slot] = (int)(p & ((1u << PK1) - 1u));
    }
    __syncthreads();

    // ---- B: gather (wave per row, 8 rounds; halves, unroll x8)
    const int w = t >> 6, L = t & 63, half = L >> 5, l32 = L & 31;
    const int ktw = l32 >> 3, qw = (l32 >> 1) & 3, jo = (l32 & 1) * 4;
    for (int r = w; r < DPB1; r += 8) {
        const int rg = b * DPB1 + r;
        if (rg < N1) {
            const int base = loff[r];
            const int n    = lcur[r] - loff[r];
            float ax = 0.f, ay = 0.f, az = 0.f, aw = 0.f;
            int i = half;
            for (; i + 14 < n; i += 16) {
                ushort4 v[8];
                #pragma unroll
                for (int u = 0; u < 8; u++) {
                    const int s = ebuf[base + i + u * 2];
                    v[u] = *(const ushort4*)(xb + (size_t)s * CIN + l32 * 4);
                }
                #pragma unroll
                for (int u = 0; u < 8; u++) {
                    ax += bf2f(v[u].x); ay += bf2f(v[u].y);
                    az += bf2f(v[u].z); aw += bf2f(v[u].w);
                }
            }
            for (; i < n; i += 2) {
                const int s = ebuf[base + i];
                const ushort4 v = *(const ushort4*)(xb + (size_t)s * CIN + l32 * 4);
                ax += bf2f(v.x); ay += bf2f(v.y); az += bf2f(v.z); aw += bf2f(v.w);
            }
            ax += __shfl_xor(ax, 32);
            ay += __shfl_xor(ay, 32);
            az += __shfl_xor(az, 32);
            aw += __shfl_xor(aw, 32);
            if (half == 0) {
                const float s = 1.0f / fmaxf((float)n, 1.0f);
                ushort4 o;
                o.x = f2bf(ax * s); o.y = f2bf(ay * s);
                o.z = f2bf(az * s); o.w = f2bf(aw * s);
                *(ushort4*)&aggT[(((ktw * DPB1 + r) * 4 + qw) * 8) + jo] = o;
            }
        }
    }
    __syncthreads();

    // ---- C: GEMM. wave w: m-tile (w&3), n-half (w>>2)
    const int m = L & 15, q = L >> 4;
    const int mt = w & 3, nh = w >> 2;
    const int row_l = mt * 16 + m;
    const int rg2 = min(b * DPB1 + row_l, N1 - 1);
    const unsigned short* a2p = xb + (size_t)rg2 * CIN + q * 8;

    f32x4 acc[8];
    #pragma unroll
    for (int nt = 0; nt < 8; nt++) acc[nt] = (f32x4){0.f, 0.f, 0.f, 0.f};

    #pragma unroll
    for (int kt = 0; kt < 8; kt++) {
        short8 af;
        if (kt < 4) af = *(const short8*)&aggT[((kt * DPB1 + row_l) * 4 + q) * 8];
        else        af = *(const short8*)(a2p + (kt - 4) * 32);
        #pragma unroll
        for (int nt = 0; nt < 8; nt++) {
            const short8 bf = *(const short8*)(
                wsw1 + (((size_t)kt * 16 + (nh * 8 + nt)) * 64 + L) * 8);
            acc[nt] = __builtin_amdgcn_mfma_f32_16x16x32_bf16(af, bf, acc[nt], 0, 0, 0);
        }
    }

    const int orow0 = b * DPB1 + mt * 16 + q * 4;
    #pragma unroll
    for (int nt = 0; nt < 8; nt++) {
        const int col = (nh * 8 + nt) * 16 + m;
        const float bv = bias[col];
        #pragma unroll
        for (int r = 0; r < 4; r++) {
            const int row = orow0 + r;
            if (row < N1) {
                const float v = fmaxf(acc[nt][r] + bv, 0.0f);
                hb[(size_t)row * HD + col] = f2bf(v);
            }
        }
    }
}

// ---------------------------------------------------------------------------
// Layer-2 mega: one block per 16-dst bucket, 512 threads. N2 = 625*16 exact.
//  B) full-wave rows (64 lanes x ushort4 = 256 cols), unroll x8
//  C) 1 m-tile, 8 waves x 2 n-tiles; fp32 out + bias, no relu.
// ---------------------------------------------------------------------------
__global__ __launch_bounds__(512) void layer2_mega(
    const unsigned short* __restrict__ hb,
    const unsigned* __restrict__ binned2, const int* __restrict__ gcnt2,
    const unsigned short* __restrict__ wsw2, const float* __restrict__ bias,
    float* __restrict__ outp)
{
    __shared__ int ebuf[CAP2];
    __shared__ int lhist[DPB2], loff[DPB2], lcur[DPB2];
    __shared__ __align__(16) unsigned short aggT[8 * DPB2 * 4 * 8];   // 8 KB

    const int t = threadIdx.x;
    const int b = blockIdx.x;
    const int cnt = gcnt2[b];
    const unsigned* bp = binned2 + (size_t)b * CAP2;

    if (t < DPB2) lhist[t] = 0;
    __syncthreads();
    for (int i = t; i < cnt; i += 512)
        atomicAdd(&lhist[bp[i] >> PK2], 1);
    __syncthreads();
    const int h0 = (t < DPB2) ? lhist[t] : 0;
    __syncthreads();
    #pragma unroll
    for (int ofs = 1; ofs < DPB2; ofs <<= 1) {
        const int u = (t >= ofs && t < DPB2) ? lhist[t - ofs] : 0;
        __syncthreads();
        if (t < DPB2) lhist[t] += u;
        __syncthreads();
    }
    if (t < DPB2) { loff[t] = lhist[t] - h0; lcur[t] = lhist[t] - h0; }
    __syncthreads();
    for (int i = t; i < cnt; i += 512) {
        const unsigned p = bp[i];
        const int slot = atomicAdd(&lcur[p >> PK2], 1);
        ebuf[slot] = (int)(p & ((1u << PK2) - 1u));
    }
    __syncthreads();

    const int w = t >> 6, L = t & 63;
    const int kt2 = L >> 3, q2 = (L >> 1) & 3, jo2 = (L & 1) * 4;
    for (int r = w; r < DPB2; r += 8) {
        const int base = loff[r];
        const int n    = lcur[r] - loff[r];
        float ax = 0.f, ay = 0.f, az = 0.f, aw = 0.f;
        int i = 0;
        for (; i + 7 < n; i += 8) {
            ushort4 v[8];
            #pragma unroll
            for (int u = 0; u < 8; u++) {
                const int s = ebuf[base + i + u];
                v[u] = *(const ushort4*)(hb + (size_t)s * HD + L * 4);
            }
            #pragma unroll
            for (int u = 0; u < 8; u++) {
                ax += bf2f(v[u].x); ay += bf2f(v[u].y);
                az += bf2f(v[u].z); aw += bf2f(v[u].w);
            }
        }
        for (; i < n; i++) {
            const int s = ebuf[base + i];
            const ushort4 v = *(const ushort4*)(hb + (size_t)s * HD + L * 4);
            ax += bf2f(v.x); ay += bf2f(v.y); az += bf2f(v.z); aw += bf2f(v.w);
        }
        const float s = 1.0f / fmaxf((float)n, 1.0f);
        ushort4 o;
        o.x = f2bf(ax * s); o.y = f2bf(ay * s);
        o.z = f2bf(az * s); o.w = f2bf(aw * s);
        *(ushort4*)&aggT[(((kt2 * DPB2 + r) * 4 + q2) * 8) + jo2] = o;
    }
    __syncthreads();

    // C: single m-tile; wave w covers n-tiles 2w, 2w+1
    const int m = L & 15, q = L >> 4;
    const int rg2 = b * DPB2 + m;          // exact, no tail
    const unsigned short* a2p = hb + (size_t)rg2 * HD + q * 8;

    f32x4 acc[2];
    acc[0] = (f32x4){0.f, 0.f, 0.f, 0.f};
    acc[1] = (f32x4){0.f, 0.f, 0.f, 0.f};

    #pragma unroll
    for (int kt = 0; kt < 16; kt++) {
        short8 af;
        if (kt < 8) af = *(const short8*)&aggT[((kt * DPB2 + m) * 4 + q) * 8];
        else        af = *(const short8*)(a2p + (kt - 8) * 32);
        #pragma unroll
        for (int nt = 0; nt < 2; nt++) {
            const short8 bf = *(const short8*)(
                wsw2 + (((size_t)kt * 16 + (w * 2 + nt)) * 64 + L) * 8);
            acc[nt] = __builtin_amdgcn_mfma_f32_16x16x32_bf16(af, bf, acc[nt], 0, 0, 0);
        }
    }

    const int orow0 = b * DPB2 + q * 4;
    #pragma unroll
    for (int nt = 0; nt < 2; nt++) {
        const int col = (w * 2 + nt) * 16 + m;
        const float bv = bias[col];
        #pragma unroll
        for (int r = 0; r < 4; r++)
            outp[(size_t)(orow0 + r) * HD + col] = acc[nt][r] + bv;
    }
}

extern "C" void kernel_launch(void* const* d_in, const int* in_sizes, int n_in,
                              void* d_out, int out_size, void* d_ws, size_t ws_size,
                              hipStream_t stream)
{
    const float* x    = (const float*)d_in[0];
    const int*   src1 = (const int*)  d_in[1];
    const int*   dst1 = (const int*)  d_in[2];
    const int*   src2 = (const int*)  d_in[3];
    const int*   dst2 = (const int*)  d_in[4];
    const float* Wl1  = (const float*)d_in[5];
    const float* Wr1  = (const float*)d_in[6];
    const float* b1   = (const float*)d_in[7];
    const float* Wl2  = (const float*)d_in[8];
    const float* Wr2  = (const float*)d_in[9];
    const float* b2   = (const float*)d_in[10];
    float* out = (float*)d_out;

    // ---- workspace (~86 MB): xb | hb | wsw1 | wsw2 | gcnt | binned1 | binned2
    unsigned short* xb   = (unsigned short*)d_ws;
    unsigned short* hb   = xb + (size_t)N0 * CIN;
    unsigned short* wsw1 = hb + (size_t)N1 * HD;
    unsigned short* wsw2 = wsw1 + 2 * CIN * HD;
    int* gcnt1 = (int*)(wsw2 + 2 * HD * HD);        // 1024
    int* gcnt2 = gcnt1 + 1024;                      // 1024
    unsigned* binned1 = (unsigned*)(gcnt2 + 1024);  // NB1*CAP1
    unsigned* binned2 = binned1 + (size_t)NB1 * CAP1;

    hipMemsetAsync(gcnt1, 0, 2048 * sizeof(int), stream);

    megaA_kernel<<<NBIN1 + NBIN2 + NPREP + NCVT, 256, 0, stream>>>(
        x, xb, Wl1, Wr1, Wl2, Wr2, wsw1, wsw2,
        src1, dst1, src2, dst2, gcnt1, gcnt2, binned1, binned2);

    layer1_mega<<<NB1, 512, 0, stream>>>(xb, binned1, gcnt1, wsw1, b1, hb);
    layer2_mega<<<NB2, 512, 0, stream>>>(hb, binned2, gcnt2, wsw2, b2, out);
}